// Round 10
// baseline (48735.190 us; speedup 1.0000x reference)
//
#include <hip/hip_runtime.h>
#include <math.h>

constexpr int BATCH = 16384;
constexpr int CDIM  = 512;
constexpr int HDIM  = 1024;
constexpr int GDIM  = 4096;   // 4*H
constexpr int TSTEP = 60;
// split-fp16 compensation: x = hi + lo*2^-11 (lo stored pre-scaled by 2^11).
// GEMM = [hi x Wlo_s | lo_s x Whi] (acc *= 2^-11) + [hi x Whi]
constexpr float LOSC  = 2048.0f;       // 2^11
constexpr float ILOSC = 1.0f / 2048.0f;

typedef _Float16 half_t;
typedef _Float16 halfx8 __attribute__((ext_vector_type(8)));
typedef _Float16 halfx4 __attribute__((ext_vector_type(4)));
typedef float    f32x4  __attribute__((ext_vector_type(4)));

__device__ __forceinline__ void async_cp16(const void* g, void* l) {
  __builtin_amdgcn_global_load_lds((__attribute__((address_space(1))) void*)g,
                                   (__attribute__((address_space(3))) void*)l,
                                   16, 0, 0);
}

__device__ __forceinline__ half_t hi16(float x) { return (half_t)x; }
__device__ __forceinline__ half_t lo16(float x) {    // pre-scaled residual
  return (half_t)((x - (float)((half_t)x)) * LOSC);
}
__device__ __forceinline__ float sigf(float x) { return 1.0f / (1.0f + expf(-x)); }
__device__ __forceinline__ float geluf(float v) {
  return 0.5f * v * (1.0f + erff(v * 0.70710678118f));
}

// XCD-aware tile swizzle (r8: neutral but harmless; kept for L2 tidiness).
__device__ __forceinline__ void swizzle_tiles(int& mt, int& nt) {
  const int gx = gridDim.x, gy = gridDim.y;
  if (gy & 7) { mt = blockIdx.x; nt = blockIdx.y; return; }
  const int lin = blockIdx.y * gx + blockIdx.x;
  const int xcd = lin & 7;
  const int slot = lin >> 3;
  const int npx = gy >> 3;
  nt = xcd * npx + (slot % npx);
  mt = slot / npx;
}

// ---------- one BK=32 step, 128x128 tile ----------
__device__ __forceinline__ void kstep(f32x4 (&acc)[4][4],
    const half_t* __restrict__ A, size_t lda, int krel,
    const half_t* __restrict__ W, size_t ldw, int kw,
    half_t* sA, half_t* sB, int bm0, int bn0) {
  const int tid  = threadIdx.x;
  const int lane = tid & 63;
  const int wave = tid >> 6;
  const int wm = wave >> 1, wn = wave & 1;
  const int ar = lane >> 2;
  const int ak = (lane & 3) * 8;
  const int quad = lane >> 4;
  const int lcol = lane & 15;
#pragma unroll
  for (int cc = 0; cc < 2; ++cc) {
    const int chunk = wave + cc * 4;
    async_cp16(A + (size_t)(bm0 + chunk * 16 + ar) * lda + (krel + ak), sA + chunk * 512);
    async_cp16(W + (size_t)(bn0 + chunk * 16 + ar) * ldw + (kw + ak), sB + chunk * 512);
  }
  asm volatile("s_waitcnt vmcnt(0)" ::: "memory");
  __syncthreads();
  halfx8 af[4], bfr[4];
#pragma unroll
  for (int mi = 0; mi < 4; ++mi)
    af[mi] = *(const halfx8*)&sA[(wm * 64 + mi * 16 + lcol) * 32 + quad * 8];
#pragma unroll
  for (int ni = 0; ni < 4; ++ni)
    bfr[ni] = *(const halfx8*)&sB[(wn * 64 + ni * 16 + lcol) * 32 + quad * 8];
#pragma unroll
  for (int mi = 0; mi < 4; ++mi)
#pragma unroll
    for (int ni = 0; ni < 4; ++ni)
      acc[mi][ni] = __builtin_amdgcn_mfma_f32_16x16x32_f16(af[mi], bfr[ni], acc[mi][ni], 0, 0, 0);
  __syncthreads();
}

__device__ __forceinline__ void scale_acc4(f32x4 (&acc)[4][4], float s) {
#pragma unroll
  for (int i = 0; i < 4; ++i)
#pragma unroll
    for (int j = 0; j < 4; ++j) acc[i][j] *= s;
}

// ---------- preamble split GEMM (K=1536: [Wlo_s x Ahi | Whi x Alo_s | Whi x Ahi])
// launch_bounds (256,3): cap VGPR ~168 -> 3 blocks/CU (m97 runs 164 VGPR / 12
// waves per CU at 874-912 TF; min=2 let the allocator float and drop to 8 waves)
template <int ACT, bool SPLITOUT>   // ACT: 0=none 1=tanh
__global__ __launch_bounds__(256, 3)
void gemm3_pre(const half_t* __restrict__ Ahi, const half_t* __restrict__ Alo,
               const half_t* __restrict__ Wcat, const float* __restrict__ bias,
               float* __restrict__ Cf, half_t* __restrict__ Chi,
               half_t* __restrict__ Clo, int ldc) {
  __shared__ __align__(16) half_t sA[128 * 32];
  __shared__ __align__(16) half_t sB[128 * 32];
  const int tid = threadIdx.x;
  int mt, nt;
  swizzle_tiles(mt, nt);
  const int bm0 = mt * 128, bn0 = nt * 128;
  f32x4 acc[4][4];
#pragma unroll
  for (int i = 0; i < 4; ++i)
#pragma unroll
    for (int j = 0; j < 4; ++j) acc[i][j] = (f32x4){0.f, 0.f, 0.f, 0.f};
#pragma unroll 1
  for (int k0 = 0; k0 < 512; k0 += 32)
    kstep(acc, Ahi, CDIM, k0, Wcat, 1536, k0, sA, sB, bm0, bn0);
#pragma unroll 1
  for (int k0 = 512; k0 < 1024; k0 += 32)
    kstep(acc, Alo, CDIM, k0 - 512, Wcat, 1536, k0, sA, sB, bm0, bn0);
  scale_acc4(acc, ILOSC);
#pragma unroll 1
  for (int k0 = 1024; k0 < 1536; k0 += 32)
    kstep(acc, Ahi, CDIM, k0 - 1024, Wcat, 1536, k0, sA, sB, bm0, bn0);

  const int lane = tid & 63, wave = tid >> 6;
  const int wm = wave >> 1, wn = wave & 1, quad = lane >> 4, lcol = lane & 15;
#pragma unroll
  for (int ni = 0; ni < 4; ++ni) {
    const int col = bn0 + wn * 64 + ni * 16 + lcol;
    const float bv = bias[col];
#pragma unroll
    for (int mi = 0; mi < 4; ++mi) {
      const int row0 = bm0 + wm * 64 + mi * 16 + quad * 4;
#pragma unroll
      for (int r = 0; r < 4; ++r) {
        float v = acc[mi][ni][r] + bv;
        if (ACT == 1) v = tanhf(v);
        const size_t idx = (size_t)(row0 + r) * ldc + col;
        if (SPLITOUT) { Chi[idx] = hi16(v); Clo[idx] = lo16(v); }
        else          { Cf[idx] = v; }
      }
    }
  }
}

// ---------- fused gates GEMM (split-K 3072, h-only) + LSTM cell + LN-stats ----------
// gctx = ctx@Wihc^T + b_ih + b_hh (fp32, interleaved cols r'=4u+g).
// extra@Wx is a rank-4 update applied in the epilogue (exact fp32).
__global__ __launch_bounds__(256, 3)
void gemm_gates_cell(const half_t* __restrict__ hAhi, const half_t* __restrict__ hAlo,
                     const half_t* __restrict__ Whh, const float* __restrict__ gctx,
                     const float* __restrict__ extra, const float* __restrict__ Wxt,
                     float* __restrict__ c, half_t* __restrict__ hBhi,
                     half_t* __restrict__ hBlo, float* __restrict__ stats) {
  __shared__ __align__(16) half_t sA[128 * 32];
  __shared__ __align__(16) half_t sB[128 * 32];
  __shared__ __align__(16) float sE[4][16 * 68];
  const int tid = threadIdx.x;
  int mt, nt;
  swizzle_tiles(mt, nt);
  const int bm0 = mt * 128, bn0 = nt * 128;
  f32x4 acc[4][4];
#pragma unroll
  for (int i = 0; i < 4; ++i)
#pragma unroll
    for (int j = 0; j < 4; ++j) acc[i][j] = (f32x4){0.f, 0.f, 0.f, 0.f};

#pragma unroll 1
  for (int k0 = 0; k0 < 1024; k0 += 32)          // hi x Wlo_s
    kstep(acc, hAhi, HDIM, k0, Whh, 3072, k0, sA, sB, bm0, bn0);
#pragma unroll 1
  for (int k0 = 1024; k0 < 2048; k0 += 32)       // lo_s x Whi
    kstep(acc, hAlo, HDIM, k0 - 1024, Whh, 3072, k0, sA, sB, bm0, bn0);
  scale_acc4(acc, ILOSC);
#pragma unroll 1
  for (int k0 = 2048; k0 < 3072; k0 += 32)       // hi x Whi
    kstep(acc, hAhi, HDIM, k0 - 2048, Whh, 3072, k0, sA, sB, bm0, bn0);

  const int lane = tid & 63, wave = tid >> 6;
  const int wm = wave >> 1, wn = wave & 1, quad = lane >> 4, lcol = lane & 15;
  float* myE = sE[wave];
  const int u = lane & 15;
  const int q = lane >> 4;
  const int j = ((bn0 + wn * 64) >> 2) + u;      // this lane's hidden unit
  const float4 wx0 = *(const float4*)(Wxt + (size_t)j * 16 + 0);
  const float4 wx1 = *(const float4*)(Wxt + (size_t)j * 16 + 4);
  const float4 wx2 = *(const float4*)(Wxt + (size_t)j * 16 + 8);
  const float4 wx3 = *(const float4*)(Wxt + (size_t)j * 16 + 12);

#pragma unroll
  for (int mi = 0; mi < 4; ++mi) {
#pragma unroll
    for (int ni = 0; ni < 4; ++ni)
#pragma unroll
      for (int r = 0; r < 4; ++r)
        myE[(quad * 4 + r) * 68 + ni * 16 + lcol] = acc[mi][ni][r];
    // same-wave DS ops are in-order: reads below see the writes above
#pragma unroll
    for (int k = 0; k < 4; ++k) {
      const int rr = q + 4 * k;
      const int row = bm0 + wm * 64 + mi * 16 + rr;
      const f32x4 gv = *(const f32x4*)&myE[rr * 68 + u * 4];  // {i,f,g,o} h-part
      const float4 gc = *(const float4*)(gctx + (size_t)row * GDIM + 4 * j);
      const float4 e  = *(const float4*)(extra + 4 * row);
      const float pi = gv[0] + gc.x + e.x*wx0.x + e.y*wx0.y + e.z*wx0.z + e.w*wx0.w;
      const float pf = gv[1] + gc.y + e.x*wx1.x + e.y*wx1.y + e.z*wx1.z + e.w*wx1.w;
      const float pg = gv[2] + gc.z + e.x*wx2.x + e.y*wx2.y + e.z*wx2.z + e.w*wx2.w;
      const float po = gv[3] + gc.w + e.x*wx3.x + e.y*wx3.y + e.z*wx3.z + e.w*wx3.w;
      const size_t cidx = (size_t)row * HDIM + j;
      const float cn = sigf(pf) * c[cidx] + sigf(pi) * tanhf(pg);
      c[cidx] = cn;
      const float vh = sigf(po) * tanhf(cn);
      hBhi[cidx] = hi16(vh);
      hBlo[cidx] = lo16(vh);
      float ps = vh, pq = vh * vh;
#pragma unroll
      for (int m = 1; m < 16; m <<= 1) {
        ps += __shfl_xor(ps, m, 64);
        pq += __shfl_xor(pq, m, 64);
      }
      if (u == 0) {
        atomicAdd(&stats[2 * row], ps);
        atomicAdd(&stats[2 * row + 1], pq);
      }
    }
  }
}

// ---------- MLP GEMM, 128x64 tile (split-K 3072): LN folded, gelu + W2-dot ----------
// delta feeds back into the recurrence via extra(t+1) -> stays 22-bit split.
__global__ __launch_bounds__(256, 3)
void gemm_mlp64(const half_t* __restrict__ hBhi, const half_t* __restrict__ hBlo,
                const half_t* __restrict__ W1g, const float* __restrict__ stats,
                const float* __restrict__ v1, const float* __restrict__ v2,
                const float* __restrict__ W2, float* __restrict__ delta) {
  __shared__ __align__(16) half_t sA[128 * 32];
  __shared__ __align__(16) half_t sB[64 * 32];
  const int tid = threadIdx.x;
  const int lane = tid & 63;
  const int wave = tid >> 6;
  const int ar = lane >> 2;
  const int ak = (lane & 3) * 8;
  const int quad = lane >> 4;
  const int lcol = lane & 15;
  int mt, nt;
  swizzle_tiles(mt, nt);
  const int bm0 = mt * 128, bn0 = nt * 64;
  f32x4 acc[2][4];
#pragma unroll
  for (int i = 0; i < 2; ++i)
#pragma unroll
    for (int jj = 0; jj < 4; ++jj) acc[i][jj] = (f32x4){0.f, 0.f, 0.f, 0.f};

  auto kstep64 = [&](const half_t* __restrict__ A, int krel, int kw) {
#pragma unroll
    for (int cc = 0; cc < 2; ++cc) {
      const int chunk = wave + cc * 4;
      async_cp16(A + (size_t)(bm0 + chunk * 16 + ar) * HDIM + (krel + ak), sA + chunk * 512);
    }
    async_cp16(W1g + (size_t)(bn0 + wave * 16 + ar) * 3072 + (kw + ak), sB + wave * 512);
    asm volatile("s_waitcnt vmcnt(0)" ::: "memory");
    __syncthreads();
    halfx8 af[2], bfr[4];
#pragma unroll
    for (int mi = 0; mi < 2; ++mi)
      af[mi] = *(const halfx8*)&sA[(wave * 32 + mi * 16 + lcol) * 32 + quad * 8];
#pragma unroll
    for (int ni = 0; ni < 4; ++ni)
      bfr[ni] = *(const halfx8*)&sB[(ni * 16 + lcol) * 32 + quad * 8];
#pragma unroll
    for (int mi = 0; mi < 2; ++mi)
#pragma unroll
      for (int ni = 0; ni < 4; ++ni)
        acc[mi][ni] = __builtin_amdgcn_mfma_f32_16x16x32_f16(af[mi], bfr[ni], acc[mi][ni], 0, 0, 0);
    __syncthreads();
  };

#pragma unroll 1
  for (int k0 = 0; k0 < 1024; k0 += 32) kstep64(hBhi, k0, k0);            // hi x Wlo_s
#pragma unroll 1
  for (int k0 = 1024; k0 < 2048; k0 += 32) kstep64(hBlo, k0 - 1024, k0);  // lo_s x Whi
#pragma unroll
  for (int i = 0; i < 2; ++i)
#pragma unroll
    for (int jj = 0; jj < 4; ++jj) acc[i][jj] *= ILOSC;
#pragma unroll 1
  for (int k0 = 2048; k0 < 3072; k0 += 32) kstep64(hBhi, k0 - 2048, k0);  // hi x Whi

  float w2a[4], w2b[4], v1c[4], v2c[4];
#pragma unroll
  for (int ni = 0; ni < 4; ++ni) {
    const int col = bn0 + ni * 16 + lcol;
    w2a[ni] = W2[col]; w2b[ni] = W2[HDIM + col];
    v1c[ni] = v1[col]; v2c[ni] = v2[col];
  }
#pragma unroll
  for (int mi = 0; mi < 2; ++mi) {
#pragma unroll
    for (int r = 0; r < 4; ++r) {
      const int row = bm0 + wave * 32 + mi * 16 + quad * 4 + r;
      const float S = stats[2 * row], Q = stats[2 * row + 1];
      const float mu = S * (1.0f / HDIM);
      const float rs = rsqrtf(Q * (1.0f / HDIM) - mu * mu + 1e-5f);
      float d0 = 0.f, d1 = 0.f;
#pragma unroll
      for (int ni = 0; ni < 4; ++ni) {
        const float g = geluf(rs * (acc[mi][ni][r] - mu * v1c[ni]) + v2c[ni]);
        d0 += g * w2a[ni];
        d1 += g * w2b[ni];
      }
#pragma unroll
      for (int m = 1; m < 16; m <<= 1) {
        d0 += __shfl_xor(d0, m, 64);
        d1 += __shfl_xor(d1, m, 64);
      }
      if (lcol == 0) {
        atomicAdd(&delta[2 * row], d0);
        atomicAdd(&delta[2 * row + 1], d1);
      }
    }
  }
}

// ---------- pos update + out write + next-step extra + zero stats/delta ----------
__global__ __launch_bounds__(256)
void finalize_step(const float* __restrict__ delta_in, const float* __restrict__ b2,
                   float* __restrict__ pos, float* __restrict__ out,
                   float* __restrict__ extra, float* __restrict__ stats,
                   float* __restrict__ delta, int t, int M) {
  const int b = blockIdx.x * 256 + threadIdx.x;
  if (b >= M) return;
  const float dx = delta_in[2*b]   + b2[0];
  const float dy = delta_in[2*b+1] + b2[1];
  const float px = pos[2*b] + dx, py = pos[2*b+1] + dy;
  pos[2*b] = px; pos[2*b+1] = py;
  out[((size_t)b * TSTEP + t) * 2 + 0] = px;
  out[((size_t)b * TSTEP + t) * 2 + 1] = py;
  const float nrm = fmaxf(sqrtf(dx*dx + dy*dy), 1e-6f);
  *(float4*)(extra + 4 * b) = make_float4(dx, dy, dx / nrm, dy / nrm);
  stats[2*b] = 0.f; stats[2*b+1] = 0.f;
  delta[2*b] = 0.f; delta[2*b+1] = 0.f;
}

// ---------- builders ----------
__global__ __launch_bounds__(256)
void cvt_split(const float* __restrict__ s, half_t* __restrict__ dhi,
               half_t* __restrict__ dlo, int n4) {
  int i = blockIdx.x * 256 + threadIdx.x;
  if (i >= n4) return;
  const float4 v = ((const float4*)s)[i];
  halfx4 h = { hi16(v.x), hi16(v.y), hi16(v.z), hi16(v.w) };
  halfx4 l = { lo16(v.x), lo16(v.y), lo16(v.z), lo16(v.w) };
  *(halfx4*)(dhi + (size_t)i * 4) = h;
  *(halfx4*)(dlo + (size_t)i * 4) = l;
}

// Whh3 [4096][3072] = [lo_s | hi | hi] of W_hh, rows interleaved r'=4u+g
__global__ __launch_bounds__(256)
void build_whh3(const float* __restrict__ Whh, half_t* __restrict__ dst) {
  int idx = blockIdx.x * 256 + threadIdx.x;
  if (idx >= GDIM * 768) return;
  const int rp = idx / 768;
  const int k  = (idx - rp * 768) * 4;
  const int sr = (rp & 3) * HDIM + (rp >> 2);
  const bool lo = (k < 1024);
  const int kk = k & 1023;
  const float4 v = *(const float4*)(Whh + (size_t)sr * HDIM + kk);
  half_t* d = dst + (size_t)rp * 3072 + k;
  if (lo) { halfx4 o = { lo16(v.x), lo16(v.y), lo16(v.z), lo16(v.w) }; *(halfx4*)d = o; }
  else    { halfx4 o = { hi16(v.x), hi16(v.y), hi16(v.z), hi16(v.w) }; *(halfx4*)d = o; }
}

// Wxt[j][g*4+c] = W_ih[g*H+j][512+c]  (rank-4 extra weights, fp32)
__global__ __launch_bounds__(256)
void build_wx(const float* __restrict__ Wih, float* __restrict__ Wxt) {
  int rp = blockIdx.x * 256 + threadIdx.x;
  if (rp >= GDIM) return;
  const int jj = rp >> 2, g = rp & 3;
  const int sr = g * HDIM + jj;
  const float4 v = *(const float4*)(Wih + (size_t)sr * 516 + 512);
  *(float4*)(Wxt + (size_t)jj * 16 + g * 4) = v;
}

// Wih_cat [4096][1536] = [lo_s | hi | hi] of W_ih[:, :512], rows interleaved
__global__ __launch_bounds__(256)
void build_wih_cat(const float* __restrict__ Wih, half_t* __restrict__ dst) {
  int idx = blockIdx.x * 256 + threadIdx.x;
  if (idx >= GDIM * 384) return;
  const int rp = idx / 384;
  const int k  = (idx - rp * 384) * 4;
  const int sr = (rp & 3) * HDIM + (rp >> 2);
  const bool lo = (k < 512);
  const int kk = lo ? k : (k < 1024 ? k - 512 : k - 1024);
  const float4 v = *(const float4*)(Wih + (size_t)sr * 516 + kk);
  half_t* d = dst + (size_t)rp * 1536 + k;
  if (lo) { halfx4 o = { lo16(v.x), lo16(v.y), lo16(v.z), lo16(v.w) }; *(halfx4*)d = o; }
  else    { halfx4 o = { hi16(v.x), hi16(v.y), hi16(v.z), hi16(v.w) }; *(halfx4*)d = o; }
}

// bias_i[r'] = b_ih[src] + b_hh[src]
__global__ __launch_bounds__(256)
void build_bias(const float* __restrict__ b_ih, const float* __restrict__ b_hh,
                float* __restrict__ bias_i) {
  int rp = blockIdx.x * 256 + threadIdx.x;
  if (rp >= GDIM) return;
  const int sr = (rp & 3) * HDIM + (rp >> 2);
  bias_i[rp] = b_ih[sr] + b_hh[sr];
}

// W1g_cat [1024][3072] = [lo_s | hi | hi] of W1*ln_g; v1=W1g·1; v2=W1·beta + b1
__global__ __launch_bounds__(256)
void build_w1g_cat(const float* __restrict__ W1, const float* __restrict__ g,
                   const float* __restrict__ beta, const float* __restrict__ b1,
                   half_t* __restrict__ W1g, float* __restrict__ v1,
                   float* __restrict__ v2) {
  const int n = blockIdx.x;
  const int tid = threadIdx.x;
  const int k = tid * 4;
  const float4 w  = *(const float4*)(W1 + (size_t)n * HDIM + k);
  const float4 gg = *(const float4*)(g + k);
  const float4 bb = *(const float4*)(beta + k);
  const float wg0 = w.x*gg.x, wg1 = w.y*gg.y, wg2 = w.z*gg.z, wg3 = w.w*gg.w;
  halfx4 hl = { lo16(wg0), lo16(wg1), lo16(wg2), lo16(wg3) };
  halfx4 hh = { hi16(wg0), hi16(wg1), hi16(wg2), hi16(wg3) };
  *(halfx4*)(W1g + (size_t)n * 3072 + k)        = hl;
  *(halfx4*)(W1g + (size_t)n * 3072 + 1024 + k) = hh;
  *(halfx4*)(W1g + (size_t)n * 3072 + 2048 + k) = hh;
  float s1 = wg0 + wg1 + wg2 + wg3;
  float s2 = w.x*bb.x + w.y*bb.y + w.z*bb.z + w.w*bb.w;
#pragma unroll
  for (int off = 32; off > 0; off >>= 1) {
    s1 += __shfl_down(s1, off, 64);
    s2 += __shfl_down(s2, off, 64);
  }
  __shared__ float t1[4], t2[4];
  const int wv = tid >> 6, ln = tid & 63;
  if (ln == 0) { t1[wv] = s1; t2[wv] = s2; }
  __syncthreads();
  if (tid == 0) {
    v1[n] = t1[0] + t1[1] + t1[2] + t1[3];
    v2[n] = t2[0] + t2[1] + t2[2] + t2[3] + b1[n];
  }
}

// Wc_cat [1024][1536] = [lo_s | hi | hi] of a [1024][512] fp32 matrix
__global__ __launch_bounds__(128)
void build_wc_cat(const float* __restrict__ W, half_t* __restrict__ dst) {
  const int n = blockIdx.x;
  const int k = threadIdx.x * 4;
  const float4 w = *(const float4*)(W + (size_t)n * CDIM + k);
  halfx4 hl = { lo16(w.x), lo16(w.y), lo16(w.z), lo16(w.w) };
  halfx4 hh = { hi16(w.x), hi16(w.y), hi16(w.z), hi16(w.w) };
  *(halfx4*)(dst + (size_t)n * 1536 + k)        = hl;
  *(halfx4*)(dst + (size_t)n * 1536 + 512 + k)  = hh;
  *(halfx4*)(dst + (size_t)n * 1536 + 1024 + k) = hh;
}

__global__ __launch_bounds__(256)
void init_chunk(const float* __restrict__ lp, const float* __restrict__ ld,
                float* __restrict__ pos, float* __restrict__ extra,
                float* __restrict__ stats, float* __restrict__ delta, int M) {
  int b = blockIdx.x * 256 + threadIdx.x;
  if (b >= M) return;
  pos[2*b]   = lp[2*b];
  pos[2*b+1] = lp[2*b+1];
  stats[2*b] = 0.f; stats[2*b+1] = 0.f;
  delta[2*b] = 0.f; delta[2*b+1] = 0.f;
  const float dx = ld[2*b], dy = ld[2*b+1];
  const float nrm = fmaxf(sqrtf(dx*dx + dy*dy), 1e-6f);
  *(float4*)(extra + 4 * b) = make_float4(dx, dy, dx / nrm, dy / nrm);
}

extern "C" void kernel_launch(void* const* d_in, const int* in_sizes, int n_in,
                              void* d_out, int out_size, void* d_ws, size_t ws_size,
                              hipStream_t stream) {
  const float* context    = (const float*)d_in[0];
  const float* last_pos   = (const float*)d_in[1];
  const float* last_delta = (const float*)d_in[2];
  const float* Wh   = (const float*)d_in[3];
  const float* bh   = (const float*)d_in[4];
  const float* Wc   = (const float*)d_in[5];
  const float* bc   = (const float*)d_in[6];
  const float* W_ih = (const float*)d_in[7];
  const float* b_ih = (const float*)d_in[8];
  const float* W_hh = (const float*)d_in[9];
  const float* b_hh = (const float*)d_in[10];
  const float* ln_g = (const float*)d_in[11];
  const float* ln_b = (const float*)d_in[12];
  const float* W1   = (const float*)d_in[13];
  const float* b1   = (const float*)d_in[14];
  const float* W2   = (const float*)d_in[15];
  const float* b2   = (const float*)d_in[16];
  float* out = (float*)d_out;

  // ---- workspace plan: static weights + per-chunk state (batch in NC chunks)
  const size_t stat_bytes =
      (size_t)GDIM * 3072 * 2 + (size_t)GDIM * 1536 * 2 + (size_t)HDIM * 3072 * 2 +
      2 * (size_t)HDIM * 1536 * 2 + (size_t)HDIM * 16 * 4 + (size_t)GDIM * 4 +
      2 * (size_t)HDIM * 4 + 16384;
  int NC = 0;
  for (int nc : {2, 4, 8, 16}) {
    const size_t M = BATCH / nc;
    const size_t chunk_bytes = 4 * M * HDIM * 2 + 2 * M * CDIM * 2 +
                               M * HDIM * 4 + (size_t)M * GDIM * 4 +
                               M * 4 * 4 + 3 * M * 2 * 4 + 16384;
    if (stat_bytes + chunk_bytes <= ws_size) { NC = nc; break; }
  }
  if (NC == 0) return;   // ws too small: stub-identical absmax = diagnostic
  const int M = BATCH / NC;

  char* w = (char*)d_ws;
  auto take = [&](size_t bytes) {
    char* p = w;
    w += (bytes + 255) & ~(size_t)255;
    return p;
  };
  half_t* Whh3    = (half_t*)take((size_t)GDIM * 3072 * 2);
  half_t* Wih_cat = (half_t*)take((size_t)GDIM * 1536 * 2);
  half_t* W1g_cat = (half_t*)take((size_t)HDIM * 3072 * 2);
  half_t* Wh_cat  = (half_t*)take((size_t)HDIM * 1536 * 2);
  half_t* Wc_cat  = (half_t*)take((size_t)HDIM * 1536 * 2);
  float*  Wxt     = (float*)take((size_t)HDIM * 16 * 4);
  float*  bias_i  = (float*)take((size_t)GDIM * 4);
  float*  v1      = (float*)take((size_t)HDIM * 4);
  float*  v2      = (float*)take((size_t)HDIM * 4);
  half_t* h0hi    = (half_t*)take((size_t)M * HDIM * 2);
  half_t* h0lo    = (half_t*)take((size_t)M * HDIM * 2);
  half_t* h1hi    = (half_t*)take((size_t)M * HDIM * 2);
  half_t* h1lo    = (half_t*)take((size_t)M * HDIM * 2);
  half_t* ctx_hi  = (half_t*)take((size_t)M * CDIM * 2);
  half_t* ctx_lo  = (half_t*)take((size_t)M * CDIM * 2);
  float*  c_f     = (float*)take((size_t)M * HDIM * 4);
  float*  gctx    = (float*)take((size_t)M * GDIM * 4);
  float*  extra   = (float*)take((size_t)M * 4 * 4);
  float*  stats   = (float*)take((size_t)M * 2 * 4);
  float*  pos_f   = (float*)take((size_t)M * 2 * 4);
  float*  delta   = (float*)take((size_t)M * 2 * 4);

  // static builders (once)
  build_whh3<<<(GDIM * 768 + 255) / 256, 256, 0, stream>>>(W_hh, Whh3);
  build_wx<<<(GDIM + 255) / 256, 256, 0, stream>>>(W_ih, Wxt);
  build_wih_cat<<<(GDIM * 384 + 255) / 256, 256, 0, stream>>>(W_ih, Wih_cat);
  build_bias<<<(GDIM + 255) / 256, 256, 0, stream>>>(b_ih, b_hh, bias_i);
  build_w1g_cat<<<HDIM, 256, 0, stream>>>(W1, ln_g, ln_b, b1, W1g_cat, v1, v2);
  build_wc_cat<<<HDIM, 128, 0, stream>>>(Wh, Wh_cat);
  build_wc_cat<<<HDIM, 128, 0, stream>>>(Wc, Wc_cat);

  const dim3 blk(256);
  for (int chunk = 0; chunk < NC; ++chunk) {
    const size_t base = (size_t)chunk * M;
    cvt_split<<<(M * CDIM / 4 + 255) / 256, 256, 0, stream>>>(
        context + base * CDIM, ctx_hi, ctx_lo, M * CDIM / 4);
    // h0 = tanh(ctx@Wh^T + bh) split-out; c0 = tanh(ctx@Wc^T + bc) fp32;
    // gctx = ctx@Wihc^T + (b_ih + b_hh) fp32 (interleaved cols)
    gemm3_pre<1, true ><<<dim3(M/128, HDIM/128), blk, 0, stream>>>(
        ctx_hi, ctx_lo, Wh_cat, bh, nullptr, h0hi, h0lo, HDIM);
    gemm3_pre<1, false><<<dim3(M/128, HDIM/128), blk, 0, stream>>>(
        ctx_hi, ctx_lo, Wc_cat, bc, c_f, nullptr, nullptr, HDIM);
    gemm3_pre<0, false><<<dim3(M/128, GDIM/128), blk, 0, stream>>>(
        ctx_hi, ctx_lo, Wih_cat, bias_i, gctx, nullptr, nullptr, GDIM);
    init_chunk<<<(M + 255) / 256, 256, 0, stream>>>(
        last_pos + base * 2, last_delta + base * 2, pos_f, extra, stats, delta, M);

    const half_t* hAhi = h0hi; const half_t* hAlo = h0lo;
    half_t* hBhi = h1hi; half_t* hBlo = h1lo;
    for (int t = 0; t < TSTEP; ++t) {
      gemm_gates_cell<<<dim3(M/128, GDIM/128), blk, 0, stream>>>(
          hAhi, hAlo, Whh3, gctx, extra, Wxt, c_f, hBhi, hBlo, stats);
      gemm_mlp64<<<dim3(M/128, HDIM/64), blk, 0, stream>>>(
          hBhi, hBlo, W1g_cat, stats, v1, v2, W2, delta);
      finalize_step<<<(M + 255) / 256, 256, 0, stream>>>(
          delta, b2, pos_f, out + base * TSTEP * 2, extra, stats, delta, t, M);
      half_t* th = hBhi; hBhi = (half_t*)hAhi; hAhi = th;
      half_t* tl = hBlo; hBlo = (half_t*)hAlo; hAlo = tl;
    }
  }
  (void)in_sizes; (void)n_in; (void)out_size;
}

// Round 11
// 48130.960 us; speedup vs baseline: 1.0126x; 1.0126x over previous
//
#include <hip/hip_runtime.h>
#include <math.h>

constexpr int BATCH = 16384;
constexpr int CDIM  = 512;
constexpr int HDIM  = 1024;
constexpr int GDIM  = 4096;   // 4*H
constexpr int TSTEP = 60;
// split-fp16 compensation: x = hi + lo*2^-11 (lo stored pre-scaled by 2^11).
// GEMM = [hi x Wlo_s | lo_s x Whi] (scaled acc, *2^-11) + [hi x Whi]
constexpr float LOSC  = 2048.0f;       // 2^11
constexpr float ILOSC = 1.0f / 2048.0f;

typedef _Float16 half_t;
typedef _Float16 halfx8 __attribute__((ext_vector_type(8)));
typedef _Float16 halfx4 __attribute__((ext_vector_type(4)));
typedef float    f32x4  __attribute__((ext_vector_type(4)));

__device__ __forceinline__ void async_cp16(const void* g, void* l) {
  __builtin_amdgcn_global_load_lds((__attribute__((address_space(1))) void*)g,
                                   (__attribute__((address_space(3))) void*)l,
                                   16, 0, 0);
}

__device__ __forceinline__ half_t hi16(float x) { return (half_t)x; }
__device__ __forceinline__ half_t lo16(float x) {    // pre-scaled residual
  return (half_t)((x - (float)((half_t)x)) * LOSC);
}
__device__ __forceinline__ float sigf(float x) { return 1.0f / (1.0f + expf(-x)); }
__device__ __forceinline__ float geluf(float v) {
  return 0.5f * v * (1.0f + erff(v * 0.70710678118f));
}

// XCD-aware tile swizzle (r8: neutral but harmless; kept).
__device__ __forceinline__ void swizzle_tiles(int& mt, int& nt) {
  const int gx = gridDim.x, gy = gridDim.y;
  if (gy & 7) { mt = blockIdx.x; nt = blockIdx.y; return; }
  const int lin = blockIdx.y * gx + blockIdx.x;
  const int xcd = lin & 7;
  const int slot = lin >> 3;
  const int npx = gy >> 3;
  nt = xcd * npx + (slot % npx);
  mt = slot / npx;
}

// ---------- one BK=32 step, 128x128 tile ----------
__device__ __forceinline__ void kstep(f32x4 (&acc)[4][4],
    const half_t* __restrict__ A, size_t lda, int krel,
    const half_t* __restrict__ W, size_t ldw, int kw,
    half_t* sA, half_t* sB, int bm0, int bn0) {
  const int tid  = threadIdx.x;
  const int lane = tid & 63;
  const int wave = tid >> 6;
  const int wm = wave >> 1, wn = wave & 1;
  const int ar = lane >> 2;
  const int ak = (lane & 3) * 8;
  const int quad = lane >> 4;
  const int lcol = lane & 15;
#pragma unroll
  for (int cc = 0; cc < 2; ++cc) {
    const int chunk = wave + cc * 4;
    async_cp16(A + (size_t)(bm0 + chunk * 16 + ar) * lda + (krel + ak), sA + chunk * 512);
    async_cp16(W + (size_t)(bn0 + chunk * 16 + ar) * ldw + (kw + ak), sB + chunk * 512);
  }
  asm volatile("s_waitcnt vmcnt(0)" ::: "memory");
  __syncthreads();
  halfx8 af[4], bfr[4];
#pragma unroll
  for (int mi = 0; mi < 4; ++mi)
    af[mi] = *(const halfx8*)&sA[(wm * 64 + mi * 16 + lcol) * 32 + quad * 8];
#pragma unroll
  for (int ni = 0; ni < 4; ++ni)
    bfr[ni] = *(const halfx8*)&sB[(wn * 64 + ni * 16 + lcol) * 32 + quad * 8];
#pragma unroll
  for (int mi = 0; mi < 4; ++mi)
#pragma unroll
    for (int ni = 0; ni < 4; ++ni)
      acc[mi][ni] = __builtin_amdgcn_mfma_f32_16x16x32_f16(af[mi], bfr[ni], acc[mi][ni], 0, 0, 0);
  __syncthreads();
}

__device__ __forceinline__ void scale_acc4(f32x4 (&acc)[4][4], float s) {
#pragma unroll
  for (int i = 0; i < 4; ++i)
#pragma unroll
    for (int j = 0; j < 4; ++j) acc[i][j] *= s;
}

// ---------- preamble split GEMM (K=1536: [Wlo_s x Ahi | Whi x Alo_s | Whi x Ahi])
template <int ACT, bool SPLITOUT>   // ACT: 0=none 1=tanh
__global__ __launch_bounds__(256, 3)
void gemm3_pre(const half_t* __restrict__ Ahi, const half_t* __restrict__ Alo,
               const half_t* __restrict__ Wcat, const float* __restrict__ bias,
               float* __restrict__ Cf, half_t* __restrict__ Chi,
               half_t* __restrict__ Clo, int ldc) {
  __shared__ __align__(16) half_t sA[128 * 32];
  __shared__ __align__(16) half_t sB[128 * 32];
  const int tid = threadIdx.x;
  int mt, nt;
  swizzle_tiles(mt, nt);
  const int bm0 = mt * 128, bn0 = nt * 128;
  f32x4 acc[4][4];
#pragma unroll
  for (int i = 0; i < 4; ++i)
#pragma unroll
    for (int j = 0; j < 4; ++j) acc[i][j] = (f32x4){0.f, 0.f, 0.f, 0.f};
#pragma unroll 1
  for (int k0 = 0; k0 < 512; k0 += 32)
    kstep(acc, Ahi, CDIM, k0, Wcat, 1536, k0, sA, sB, bm0, bn0);
#pragma unroll 1
  for (int k0 = 512; k0 < 1024; k0 += 32)
    kstep(acc, Alo, CDIM, k0 - 512, Wcat, 1536, k0, sA, sB, bm0, bn0);
  scale_acc4(acc, ILOSC);
#pragma unroll 1
  for (int k0 = 1024; k0 < 1536; k0 += 32)
    kstep(acc, Ahi, CDIM, k0 - 1024, Wcat, 1536, k0, sA, sB, bm0, bn0);

  const int lane = tid & 63, wave = tid >> 6;
  const int wm = wave >> 1, wn = wave & 1, quad = lane >> 4, lcol = lane & 15;
#pragma unroll
  for (int ni = 0; ni < 4; ++ni) {
    const int col = bn0 + wn * 64 + ni * 16 + lcol;
    const float bv = bias[col];
#pragma unroll
    for (int mi = 0; mi < 4; ++mi) {
      const int row0 = bm0 + wm * 64 + mi * 16 + quad * 4;
#pragma unroll
      for (int r = 0; r < 4; ++r) {
        float v = acc[mi][ni][r] + bv;
        if (ACT == 1) v = tanhf(v);
        const size_t idx = (size_t)(row0 + r) * ldc + col;
        if (SPLITOUT) { Chi[idx] = hi16(v); Clo[idx] = lo16(v); }
        else          { Cf[idx] = v; }
      }
    }
  }
}

// ---------- fused gates GEMM (split-K 3072, h-only) + LSTM cell + LN-stats ----------
// gctx = ctx@Wihc^T + b_ih + b_hh (fp32, interleaved cols r'=4u+g).
// extra is derived inline from dprev (previous step's delta atomics) + b2.
// launch_bounds (256,4): 1024 tiles = exactly 4 blocks/CU x 256 CUs (3/CU left
// a 256-block tail round at 1/CU). Revert to 3 if VGPR spill regresses.
__global__ __launch_bounds__(256, 4)
void gemm_gates_cell(const half_t* __restrict__ hAhi, const half_t* __restrict__ hAlo,
                     const half_t* __restrict__ Whh, const float* __restrict__ gctx,
                     const float* __restrict__ dprev, const float* __restrict__ b2,
                     const float* __restrict__ Wxt,
                     float* __restrict__ c, half_t* __restrict__ hBhi,
                     half_t* __restrict__ hBlo, float* __restrict__ statsT) {
  __shared__ __align__(16) half_t sA[128 * 32];
  __shared__ __align__(16) half_t sB[128 * 32];
  __shared__ __align__(16) float sE[4][16 * 68];
  const int tid = threadIdx.x;
  int mt, nt;
  swizzle_tiles(mt, nt);
  const int bm0 = mt * 128, bn0 = nt * 128;
  f32x4 acc[4][4];
#pragma unroll
  for (int i = 0; i < 4; ++i)
#pragma unroll
    for (int j = 0; j < 4; ++j) acc[i][j] = (f32x4){0.f, 0.f, 0.f, 0.f};

#pragma unroll 1
  for (int k0 = 0; k0 < 1024; k0 += 32)          // hi x Wlo_s
    kstep(acc, hAhi, HDIM, k0, Whh, 3072, k0, sA, sB, bm0, bn0);
#pragma unroll 1
  for (int k0 = 1024; k0 < 2048; k0 += 32)       // lo_s x Whi
    kstep(acc, hAlo, HDIM, k0 - 1024, Whh, 3072, k0, sA, sB, bm0, bn0);
  scale_acc4(acc, ILOSC);
#pragma unroll 1
  for (int k0 = 2048; k0 < 3072; k0 += 32)       // hi x Whi
    kstep(acc, hAhi, HDIM, k0 - 2048, Whh, 3072, k0, sA, sB, bm0, bn0);

  const int lane = tid & 63, wave = tid >> 6;
  const int wm = wave >> 1, wn = wave & 1, quad = lane >> 4, lcol = lane & 15;
  float* myE = sE[wave];
  const int u = lane & 15;
  const int q = lane >> 4;
  const int j = ((bn0 + wn * 64) >> 2) + u;      // this lane's hidden unit
  const float b20 = b2[0], b21 = b2[1];
  const float4 wx0 = *(const float4*)(Wxt + (size_t)j * 16 + 0);
  const float4 wx1 = *(const float4*)(Wxt + (size_t)j * 16 + 4);
  const float4 wx2 = *(const float4*)(Wxt + (size_t)j * 16 + 8);
  const float4 wx3 = *(const float4*)(Wxt + (size_t)j * 16 + 12);

#pragma unroll
  for (int mi = 0; mi < 4; ++mi) {
#pragma unroll
    for (int ni = 0; ni < 4; ++ni)
#pragma unroll
      for (int r = 0; r < 4; ++r)
        myE[(quad * 4 + r) * 68 + ni * 16 + lcol] = acc[mi][ni][r];
    // same-wave DS ops are in-order: reads below see the writes above
#pragma unroll
    for (int k = 0; k < 4; ++k) {
      const int rr = q + 4 * k;
      const int row = bm0 + wm * 64 + mi * 16 + rr;
      const f32x4 gv = *(const f32x4*)&myE[rr * 68 + u * 4];  // {i,f,g,o} h-part
      const float4 gc = *(const float4*)(gctx + (size_t)row * GDIM + 4 * j);
      const float dx = dprev[2 * row] + b20;
      const float dy = dprev[2 * row + 1] + b21;
      const float nrm = fmaxf(sqrtf(dx * dx + dy * dy), 1e-6f);
      const float ex = dx, ey = dy, ehx = dx / nrm, ehy = dy / nrm;
      const float pi = gv[0] + gc.x + ex*wx0.x + ey*wx0.y + ehx*wx0.z + ehy*wx0.w;
      const float pf = gv[1] + gc.y + ex*wx1.x + ey*wx1.y + ehx*wx1.z + ehy*wx1.w;
      const float pg = gv[2] + gc.z + ex*wx2.x + ey*wx2.y + ehx*wx2.z + ehy*wx2.w;
      const float po = gv[3] + gc.w + ex*wx3.x + ey*wx3.y + ehx*wx3.z + ehy*wx3.w;
      const size_t cidx = (size_t)row * HDIM + j;
      const float cn = sigf(pf) * c[cidx] + sigf(pi) * tanhf(pg);
      c[cidx] = cn;
      const float vh = sigf(po) * tanhf(cn);
      hBhi[cidx] = hi16(vh);
      hBlo[cidx] = lo16(vh);
      float ps = vh, pq = vh * vh;
#pragma unroll
      for (int m = 1; m < 16; m <<= 1) {
        ps += __shfl_xor(ps, m, 64);
        pq += __shfl_xor(pq, m, 64);
      }
      if (u == 0) {
        atomicAdd(&statsT[2 * row], ps);
        atomicAdd(&statsT[2 * row + 1], pq);
      }
    }
  }
}

// ---------- MLP GEMM, 128x64 tile, paired-W kstep ----------
// W1g2 [1024][2048] = [lo_s | hi]. Paired phase stages the A_hi tile ONCE
// against both W_lo (scaled acc) and W_hi (main acc): 16 MFMA / 4 loads per
// barrier (was 8 / 3), 64 barriers total (was 96). Remainder: A_lo x W_hi.
// delta feeds back into the recurrence via extra(t+1) -> stays 22-bit split.
__global__ __launch_bounds__(256, 3)
void gemm_mlp64(const half_t* __restrict__ hBhi, const half_t* __restrict__ hBlo,
                const half_t* __restrict__ W1g, const float* __restrict__ statsT,
                const float* __restrict__ v1, const float* __restrict__ v2,
                const float* __restrict__ W2, float* __restrict__ deltaT) {
  __shared__ __align__(16) half_t sA[128 * 32];
  __shared__ __align__(16) half_t sBl[64 * 32];
  __shared__ __align__(16) half_t sBh[64 * 32];
  const int tid = threadIdx.x;
  const int lane = tid & 63;
  const int wave = tid >> 6;
  const int ar = lane >> 2;
  const int ak = (lane & 3) * 8;
  const int quad = lane >> 4;
  const int lcol = lane & 15;
  int mt, nt;
  swizzle_tiles(mt, nt);
  const int bm0 = mt * 128, bn0 = nt * 64;
  f32x4 accS[2][4], accM[2][4];
#pragma unroll
  for (int i = 0; i < 2; ++i)
#pragma unroll
    for (int jj = 0; jj < 4; ++jj) {
      accS[i][jj] = (f32x4){0.f, 0.f, 0.f, 0.f};
      accM[i][jj] = (f32x4){0.f, 0.f, 0.f, 0.f};
    }

  // paired phase: A_hi x {W_lo_s -> accS, W_hi -> accM}
#pragma unroll 1
  for (int k0 = 0; k0 < 1024; k0 += 32) {
#pragma unroll
    for (int cc = 0; cc < 2; ++cc) {
      const int chunk = wave + cc * 4;
      async_cp16(hBhi + (size_t)(bm0 + chunk * 16 + ar) * HDIM + (k0 + ak), sA + chunk * 512);
    }
    async_cp16(W1g + (size_t)(bn0 + wave * 16 + ar) * 2048 + (k0 + ak), sBl + wave * 512);
    async_cp16(W1g + (size_t)(bn0 + wave * 16 + ar) * 2048 + (1024 + k0 + ak), sBh + wave * 512);
    asm volatile("s_waitcnt vmcnt(0)" ::: "memory");
    __syncthreads();
    halfx8 af[2], bl[4], bh[4];
#pragma unroll
    for (int mi = 0; mi < 2; ++mi)
      af[mi] = *(const halfx8*)&sA[(wave * 32 + mi * 16 + lcol) * 32 + quad * 8];
#pragma unroll
    for (int ni = 0; ni < 4; ++ni) {
      bl[ni] = *(const halfx8*)&sBl[(ni * 16 + lcol) * 32 + quad * 8];
      bh[ni] = *(const halfx8*)&sBh[(ni * 16 + lcol) * 32 + quad * 8];
    }
#pragma unroll
    for (int mi = 0; mi < 2; ++mi)
#pragma unroll
      for (int ni = 0; ni < 4; ++ni) {
        accS[mi][ni] = __builtin_amdgcn_mfma_f32_16x16x32_f16(af[mi], bl[ni], accS[mi][ni], 0, 0, 0);
        accM[mi][ni] = __builtin_amdgcn_mfma_f32_16x16x32_f16(af[mi], bh[ni], accM[mi][ni], 0, 0, 0);
      }
    __syncthreads();
  }
  // remainder: A_lo_s x W_hi -> accS
#pragma unroll 1
  for (int k0 = 0; k0 < 1024; k0 += 32) {
#pragma unroll
    for (int cc = 0; cc < 2; ++cc) {
      const int chunk = wave + cc * 4;
      async_cp16(hBlo + (size_t)(bm0 + chunk * 16 + ar) * HDIM + (k0 + ak), sA + chunk * 512);
    }
    async_cp16(W1g + (size_t)(bn0 + wave * 16 + ar) * 2048 + (1024 + k0 + ak), sBl + wave * 512);
    asm volatile("s_waitcnt vmcnt(0)" ::: "memory");
    __syncthreads();
    halfx8 af[2], bl[4];
#pragma unroll
    for (int mi = 0; mi < 2; ++mi)
      af[mi] = *(const halfx8*)&sA[(wave * 32 + mi * 16 + lcol) * 32 + quad * 8];
#pragma unroll
    for (int ni = 0; ni < 4; ++ni)
      bl[ni] = *(const halfx8*)&sBl[(ni * 16 + lcol) * 32 + quad * 8];
#pragma unroll
    for (int mi = 0; mi < 2; ++mi)
#pragma unroll
      for (int ni = 0; ni < 4; ++ni)
        accS[mi][ni] = __builtin_amdgcn_mfma_f32_16x16x32_f16(af[mi], bl[ni], accS[mi][ni], 0, 0, 0);
    __syncthreads();
  }
#pragma unroll
  for (int i = 0; i < 2; ++i)
#pragma unroll
    for (int jj = 0; jj < 4; ++jj) accM[i][jj] += accS[i][jj] * ILOSC;

  float w2a[4], w2b[4], v1c[4], v2c[4];
#pragma unroll
  for (int ni = 0; ni < 4; ++ni) {
    const int col = bn0 + ni * 16 + lcol;
    w2a[ni] = W2[col]; w2b[ni] = W2[HDIM + col];
    v1c[ni] = v1[col]; v2c[ni] = v2[col];
  }
#pragma unroll
  for (int mi = 0; mi < 2; ++mi) {
#pragma unroll
    for (int r = 0; r < 4; ++r) {
      const int row = bm0 + wave * 32 + mi * 16 + quad * 4 + r;
      const float S = statsT[2 * row], Q = statsT[2 * row + 1];
      const float mu = S * (1.0f / HDIM);
      const float rs = rsqrtf(Q * (1.0f / HDIM) - mu * mu + 1e-5f);
      float d0 = 0.f, d1 = 0.f;
#pragma unroll
      for (int ni = 0; ni < 4; ++ni) {
        const float g = geluf(rs * (accM[mi][ni][r] - mu * v1c[ni]) + v2c[ni]);
        d0 += g * w2a[ni];
        d1 += g * w2b[ni];
      }
#pragma unroll
      for (int m = 1; m < 16; m <<= 1) {
        d0 += __shfl_xor(d0, m, 64);
        d1 += __shfl_xor(d1, m, 64);
      }
      if (lcol == 0) {
        atomicAdd(&deltaT[2 * row], d0);
        atomicAdd(&deltaT[2 * row + 1], d1);
      }
    }
  }
}

// ---------- trajectory writeback: pos cumsum + out (once per chunk) ----------
__global__ __launch_bounds__(256)
void write_traj(const float* __restrict__ lp, const float* __restrict__ deltaT,
                const float* __restrict__ b2, float* __restrict__ out, int M) {
  const int b = blockIdx.x * 256 + threadIdx.x;
  if (b >= M) return;
  float px = lp[2 * b], py = lp[2 * b + 1];
  const float b20 = b2[0], b21 = b2[1];
  for (int t = 0; t < TSTEP; ++t) {
    px += deltaT[(size_t)t * M * 2 + 2 * b] + b20;
    py += deltaT[(size_t)t * M * 2 + 2 * b + 1] + b21;
    out[((size_t)b * TSTEP + t) * 2 + 0] = px;
    out[((size_t)b * TSTEP + t) * 2 + 1] = py;
  }
}

// ---------- builders ----------
__global__ __launch_bounds__(256)
void cvt_split(const float* __restrict__ s, half_t* __restrict__ dhi,
               half_t* __restrict__ dlo, int n4) {
  int i = blockIdx.x * 256 + threadIdx.x;
  if (i >= n4) return;
  const float4 v = ((const float4*)s)[i];
  halfx4 h = { hi16(v.x), hi16(v.y), hi16(v.z), hi16(v.w) };
  halfx4 l = { lo16(v.x), lo16(v.y), lo16(v.z), lo16(v.w) };
  *(halfx4*)(dhi + (size_t)i * 4) = h;
  *(halfx4*)(dlo + (size_t)i * 4) = l;
}

// Whh3 [4096][3072] = [lo_s | hi | hi] of W_hh, rows interleaved r'=4u+g
__global__ __launch_bounds__(256)
void build_whh3(const float* __restrict__ Whh, half_t* __restrict__ dst) {
  int idx = blockIdx.x * 256 + threadIdx.x;
  if (idx >= GDIM * 768) return;
  const int rp = idx / 768;
  const int k  = (idx - rp * 768) * 4;
  const int sr = (rp & 3) * HDIM + (rp >> 2);
  const bool lo = (k < 1024);
  const int kk = k & 1023;
  const float4 v = *(const float4*)(Whh + (size_t)sr * HDIM + kk);
  half_t* d = dst + (size_t)rp * 3072 + k;
  if (lo) { halfx4 o = { lo16(v.x), lo16(v.y), lo16(v.z), lo16(v.w) }; *(halfx4*)d = o; }
  else    { halfx4 o = { hi16(v.x), hi16(v.y), hi16(v.z), hi16(v.w) }; *(halfx4*)d = o; }
}

// Wxt[j][g*4+c] = W_ih[g*H+j][512+c]  (rank-4 extra weights, fp32)
__global__ __launch_bounds__(256)
void build_wx(const float* __restrict__ Wih, float* __restrict__ Wxt) {
  int rp = blockIdx.x * 256 + threadIdx.x;
  if (rp >= GDIM) return;
  const int jj = rp >> 2, g = rp & 3;
  const int sr = g * HDIM + jj;
  const float4 v = *(const float4*)(Wih + (size_t)sr * 516 + 512);
  *(float4*)(Wxt + (size_t)jj * 16 + g * 4) = v;
}

// Wih_cat [4096][1536] = [lo_s | hi | hi] of W_ih[:, :512], rows interleaved
__global__ __launch_bounds__(256)
void build_wih_cat(const float* __restrict__ Wih, half_t* __restrict__ dst) {
  int idx = blockIdx.x * 256 + threadIdx.x;
  if (idx >= GDIM * 384) return;
  const int rp = idx / 384;
  const int k  = (idx - rp * 384) * 4;
  const int sr = (rp & 3) * HDIM + (rp >> 2);
  const bool lo = (k < 512);
  const int kk = lo ? k : (k < 1024 ? k - 512 : k - 1024);
  const float4 v = *(const float4*)(Wih + (size_t)sr * 516 + kk);
  half_t* d = dst + (size_t)rp * 1536 + k;
  if (lo) { halfx4 o = { lo16(v.x), lo16(v.y), lo16(v.z), lo16(v.w) }; *(halfx4*)d = o; }
  else    { halfx4 o = { hi16(v.x), hi16(v.y), hi16(v.z), hi16(v.w) }; *(halfx4*)d = o; }
}

// bias_i[r'] = b_ih[src] + b_hh[src]
__global__ __launch_bounds__(256)
void build_bias(const float* __restrict__ b_ih, const float* __restrict__ b_hh,
                float* __restrict__ bias_i) {
  int rp = blockIdx.x * 256 + threadIdx.x;
  if (rp >= GDIM) return;
  const int sr = (rp & 3) * HDIM + (rp >> 2);
  bias_i[rp] = b_ih[sr] + b_hh[sr];
}

// W1g2 [1024][2048] = [lo_s | hi] of W1*ln_g; v1=W1g·1; v2=W1·beta + b1
__global__ __launch_bounds__(256)
void build_w1g2(const float* __restrict__ W1, const float* __restrict__ g,
                const float* __restrict__ beta, const float* __restrict__ b1,
                half_t* __restrict__ W1g, float* __restrict__ v1,
                float* __restrict__ v2) {
  const int n = blockIdx.x;
  const int tid = threadIdx.x;
  const int k = tid * 4;
  const float4 w  = *(const float4*)(W1 + (size_t)n * HDIM + k);
  const float4 gg = *(const float4*)(g + k);
  const float4 bb = *(const float4*)(beta + k);
  const float wg0 = w.x*gg.x, wg1 = w.y*gg.y, wg2 = w.z*gg.z, wg3 = w.w*gg.w;
  halfx4 hl = { lo16(wg0), lo16(wg1), lo16(wg2), lo16(wg3) };
  halfx4 hh = { hi16(wg0), hi16(wg1), hi16(wg2), hi16(wg3) };
  *(halfx4*)(W1g + (size_t)n * 2048 + k)        = hl;
  *(halfx4*)(W1g + (size_t)n * 2048 + 1024 + k) = hh;
  float s1 = wg0 + wg1 + wg2 + wg3;
  float s2 = w.x*bb.x + w.y*bb.y + w.z*bb.z + w.w*bb.w;
#pragma unroll
  for (int off = 32; off > 0; off >>= 1) {
    s1 += __shfl_down(s1, off, 64);
    s2 += __shfl_down(s2, off, 64);
  }
  __shared__ float t1[4], t2[4];
  const int wv = tid >> 6, ln = tid & 63;
  if (ln == 0) { t1[wv] = s1; t2[wv] = s2; }
  __syncthreads();
  if (tid == 0) {
    v1[n] = t1[0] + t1[1] + t1[2] + t1[3];
    v2[n] = t2[0] + t2[1] + t2[2] + t2[3] + b1[n];
  }
}

// Wc_cat [1024][1536] = [lo_s | hi | hi] of a [1024][512] fp32 matrix
__global__ __launch_bounds__(128)
void build_wc_cat(const float* __restrict__ W, half_t* __restrict__ dst) {
  const int n = blockIdx.x;
  const int k = threadIdx.x * 4;
  const float4 w = *(const float4*)(W + (size_t)n * CDIM + k);
  halfx4 hl = { lo16(w.x), lo16(w.y), lo16(w.z), lo16(w.w) };
  halfx4 hh = { hi16(w.x), hi16(w.y), hi16(w.z), hi16(w.w) };
  *(halfx4*)(dst + (size_t)n * 1536 + k)        = hl;
  *(halfx4*)(dst + (size_t)n * 1536 + 512 + k)  = hh;
  *(halfx4*)(dst + (size_t)n * 1536 + 1024 + k) = hh;
}

// delta_init = last_delta - b2, so gates t=0 recovers extra from it exactly
__global__ __launch_bounds__(256)
void init_chunk(const float* __restrict__ ld, const float* __restrict__ b2,
                float* __restrict__ delta_init, int M) {
  int b = blockIdx.x * 256 + threadIdx.x;
  if (b >= M) return;
  delta_init[2*b]   = ld[2*b]   - b2[0];
  delta_init[2*b+1] = ld[2*b+1] - b2[1];
}

extern "C" void kernel_launch(void* const* d_in, const int* in_sizes, int n_in,
                              void* d_out, int out_size, void* d_ws, size_t ws_size,
                              hipStream_t stream) {
  const float* context    = (const float*)d_in[0];
  const float* last_pos   = (const float*)d_in[1];
  const float* last_delta = (const float*)d_in[2];
  const float* Wh   = (const float*)d_in[3];
  const float* bh   = (const float*)d_in[4];
  const float* Wc   = (const float*)d_in[5];
  const float* bc   = (const float*)d_in[6];
  const float* W_ih = (const float*)d_in[7];
  const float* b_ih = (const float*)d_in[8];
  const float* W_hh = (const float*)d_in[9];
  const float* b_hh = (const float*)d_in[10];
  const float* ln_g = (const float*)d_in[11];
  const float* ln_b = (const float*)d_in[12];
  const float* W1   = (const float*)d_in[13];
  const float* b1   = (const float*)d_in[14];
  const float* W2   = (const float*)d_in[15];
  const float* b2   = (const float*)d_in[16];
  float* out = (float*)d_out;

  // ---- workspace plan: static weights + per-chunk state (batch in NC chunks)
  const size_t stat_bytes =
      (size_t)GDIM * 3072 * 2 + (size_t)GDIM * 1536 * 2 + (size_t)HDIM * 2048 * 2 +
      2 * (size_t)HDIM * 1536 * 2 + (size_t)HDIM * 16 * 4 + (size_t)GDIM * 4 +
      2 * (size_t)HDIM * 4 + 16384;
  int NC = 0;
  for (int nc : {2, 4, 8, 16}) {
    const size_t M = BATCH / nc;
    const size_t chunk_bytes = 4 * M * HDIM * 2 + 2 * M * CDIM * 2 +
                               M * HDIM * 4 + (size_t)M * GDIM * 4 +
                               M * 2 * 4 + 2 * (size_t)TSTEP * M * 2 * 4 + 16384;
    if (stat_bytes + chunk_bytes <= ws_size) { NC = nc; break; }
  }
  if (NC == 0) return;   // ws too small: stub-identical absmax = diagnostic
  const int M = BATCH / NC;

  char* w = (char*)d_ws;
  auto take = [&](size_t bytes) {
    char* p = w;
    w += (bytes + 255) & ~(size_t)255;
    return p;
  };
  half_t* Whh3    = (half_t*)take((size_t)GDIM * 3072 * 2);
  half_t* Wih_cat = (half_t*)take((size_t)GDIM * 1536 * 2);
  half_t* W1g2    = (half_t*)take((size_t)HDIM * 2048 * 2);
  half_t* Wh_cat  = (half_t*)take((size_t)HDIM * 1536 * 2);
  half_t* Wc_cat  = (half_t*)take((size_t)HDIM * 1536 * 2);
  float*  Wxt     = (float*)take((size_t)HDIM * 16 * 4);
  float*  bias_i  = (float*)take((size_t)GDIM * 4);
  float*  v1      = (float*)take((size_t)HDIM * 4);
  float*  v2      = (float*)take((size_t)HDIM * 4);
  half_t* h0hi    = (half_t*)take((size_t)M * HDIM * 2);
  half_t* h0lo    = (half_t*)take((size_t)M * HDIM * 2);
  half_t* h1hi    = (half_t*)take((size_t)M * HDIM * 2);
  half_t* h1lo    = (half_t*)take((size_t)M * HDIM * 2);
  half_t* ctx_hi  = (half_t*)take((size_t)M * CDIM * 2);
  half_t* ctx_lo  = (half_t*)take((size_t)M * CDIM * 2);
  float*  c_f     = (float*)take((size_t)M * HDIM * 4);
  float*  gctx    = (float*)take((size_t)M * GDIM * 4);
  float*  dinit   = (float*)take((size_t)M * 2 * 4);
  const size_t sd_bytes = 2 * (size_t)TSTEP * M * 2 * 4;
  float*  statsAll = (float*)take(sd_bytes);            // [60][M][2] stats
  float*  deltaAll = statsAll + (size_t)TSTEP * M * 2;  // [60][M][2] delta

  // static builders (once)
  build_whh3<<<(GDIM * 768 + 255) / 256, 256, 0, stream>>>(W_hh, Whh3);
  build_wx<<<(GDIM + 255) / 256, 256, 0, stream>>>(W_ih, Wxt);
  build_wih_cat<<<(GDIM * 384 + 255) / 256, 256, 0, stream>>>(W_ih, Wih_cat);
  build_bias<<<(GDIM + 255) / 256, 256, 0, stream>>>(b_ih, b_hh, bias_i);
  build_w1g2<<<HDIM, 256, 0, stream>>>(W1, ln_g, ln_b, b1, W1g2, v1, v2);
  build_wc_cat<<<HDIM, 128, 0, stream>>>(Wh, Wh_cat);
  build_wc_cat<<<HDIM, 128, 0, stream>>>(Wc, Wc_cat);

  const dim3 blk(256);
  for (int chunk = 0; chunk < NC; ++chunk) {
    const size_t base = (size_t)chunk * M;
    hipMemsetAsync(statsAll, 0, sd_bytes, stream);   // zero stats+delta slices
    cvt_split<<<(M * CDIM / 4 + 255) / 256, 256, 0, stream>>>(
        context + base * CDIM, ctx_hi, ctx_lo, M * CDIM / 4);
    gemm3_pre<1, true ><<<dim3(M/128, HDIM/128), blk, 0, stream>>>(
        ctx_hi, ctx_lo, Wh_cat, bh, nullptr, h0hi, h0lo, HDIM);
    gemm3_pre<1, false><<<dim3(M/128, HDIM/128), blk, 0, stream>>>(
        ctx_hi, ctx_lo, Wc_cat, bc, c_f, nullptr, nullptr, HDIM);
    gemm3_pre<0, false><<<dim3(M/128, GDIM/128), blk, 0, stream>>>(
        ctx_hi, ctx_lo, Wih_cat, bias_i, gctx, nullptr, nullptr, GDIM);
    init_chunk<<<(M + 255) / 256, 256, 0, stream>>>(
        last_delta + base * 2, b2, dinit, M);

    const half_t* hAhi = h0hi; const half_t* hAlo = h0lo;
    half_t* hBhi = h1hi; half_t* hBlo = h1lo;
    for (int t = 0; t < TSTEP; ++t) {
      const float* dprev = (t == 0) ? dinit : deltaAll + (size_t)(t - 1) * M * 2;
      gemm_gates_cell<<<dim3(M/128, GDIM/128), blk, 0, stream>>>(
          hAhi, hAlo, Whh3, gctx, dprev, b2, Wxt, c_f, hBhi, hBlo,
          statsAll + (size_t)t * M * 2);
      gemm_mlp64<<<dim3(M/128, HDIM/64), blk, 0, stream>>>(
          hBhi, hBlo, W1g2, statsAll + (size_t)t * M * 2, v1, v2, W2,
          deltaAll + (size_t)t * M * 2);
      half_t* th = hBhi; hBhi = (half_t*)hAhi; hAhi = th;
      half_t* tl = hBlo; hBlo = (half_t*)hAlo; hAlo = tl;
    }
    write_traj<<<(M + 255) / 256, 256, 0, stream>>>(
        last_pos + base * 2, deltaAll, b2, out + base * TSTEP * 2, M);
  }
  (void)in_sizes; (void)n_in; (void)out_size;
}

// Round 12
// 38794.446 us; speedup vs baseline: 1.2562x; 1.2407x over previous
//
#include <hip/hip_runtime.h>
#include <math.h>

constexpr int BATCH = 16384;
constexpr int CDIM  = 512;
constexpr int HDIM  = 1024;
constexpr int GDIM  = 4096;   // 4*H
constexpr int TSTEP = 60;
// split-fp16: x = hi + lo (|lo| <= 2^-12). Gates GEMM hybrid:
//   main:        hi x Whi   fp16 MFMA, f32 acc (products exact in f32)
//   corrections: hi x Wlo + lo x Whi  as ONE int8 GEMM (2x rate), both
//   cross-terms quantized to a shared 2^(25-E) fixed-point scale.
constexpr float LOSC  = 2048.0f;       // 2^11 (fp16 lo limb pre-scale)
constexpr float ILOSC = 1.0f / 2048.0f;

typedef _Float16 half_t;
typedef _Float16 halfx8 __attribute__((ext_vector_type(8)));
typedef _Float16 halfx4 __attribute__((ext_vector_type(4)));
typedef float    f32x4  __attribute__((ext_vector_type(4)));
typedef int      i32x4  __attribute__((ext_vector_type(4)));
typedef signed char i8_t;

__device__ __forceinline__ void async_cp16(const void* g, void* l) {
  __builtin_amdgcn_global_load_lds((__attribute__((address_space(1))) void*)g,
                                   (__attribute__((address_space(3))) void*)l,
                                   16, 0, 0);
}

__device__ __forceinline__ half_t hi16(float x) { return (half_t)x; }
__device__ __forceinline__ half_t lo16(float x) {
  return (half_t)((x - (float)((half_t)x)) * LOSC);
}
__device__ __forceinline__ int clamp8(int v) {
  return v > 127 ? 127 : (v < -127 ? -127 : v);
}
__device__ __forceinline__ float sigf(float x) { return 1.0f / (1.0f + expf(-x)); }
__device__ __forceinline__ float geluf(float v) {
  return 0.5f * v * (1.0f + erff(v * 0.70710678118f));
}

// XCD-aware tile swizzle (r8: neutral but harmless; kept).
__device__ __forceinline__ void swizzle_tiles(int& mt, int& nt) {
  const int gx = gridDim.x, gy = gridDim.y;
  if (gy & 7) { mt = blockIdx.x; nt = blockIdx.y; return; }
  const int lin = blockIdx.y * gx + blockIdx.x;
  const int xcd = lin & 7;
  const int slot = lin >> 3;
  const int npx = gy >> 3;
  nt = xcd * npx + (slot % npx);
  mt = slot / npx;
}

// ---------- one BK=32 fp16 step, 128x128 tile ----------
__device__ __forceinline__ void kstep(f32x4 (&acc)[4][4],
    const half_t* __restrict__ A, size_t lda, int krel,
    const half_t* __restrict__ W, size_t ldw, int kw,
    half_t* sA, half_t* sB, int bm0, int bn0) {
  const int tid  = threadIdx.x;
  const int lane = tid & 63;
  const int wave = tid >> 6;
  const int wm = wave >> 1, wn = wave & 1;
  const int ar = lane >> 2;
  const int ak = (lane & 3) * 8;
  const int quad = lane >> 4;
  const int lcol = lane & 15;
#pragma unroll
  for (int cc = 0; cc < 2; ++cc) {
    const int chunk = wave + cc * 4;
    async_cp16(A + (size_t)(bm0 + chunk * 16 + ar) * lda + (krel + ak), sA + chunk * 512);
    async_cp16(W + (size_t)(bn0 + chunk * 16 + ar) * ldw + (kw + ak), sB + chunk * 512);
  }
  asm volatile("s_waitcnt vmcnt(0)" ::: "memory");
  __syncthreads();
  halfx8 af[4], bfr[4];
#pragma unroll
  for (int mi = 0; mi < 4; ++mi)
    af[mi] = *(const halfx8*)&sA[(wm * 64 + mi * 16 + lcol) * 32 + quad * 8];
#pragma unroll
  for (int ni = 0; ni < 4; ++ni)
    bfr[ni] = *(const halfx8*)&sB[(wn * 64 + ni * 16 + lcol) * 32 + quad * 8];
#pragma unroll
  for (int mi = 0; mi < 4; ++mi)
#pragma unroll
    for (int ni = 0; ni < 4; ++ni)
      acc[mi][ni] = __builtin_amdgcn_mfma_f32_16x16x32_f16(af[mi], bfr[ni], acc[mi][ni], 0, 0, 0);
  __syncthreads();
}

__device__ __forceinline__ void scale_acc4(f32x4 (&acc)[4][4], float s) {
#pragma unroll
  for (int i = 0; i < 4; ++i)
#pragma unroll
    for (int j = 0; j < 4; ++j) acc[i][j] *= s;
}

// ---------- preamble split GEMM (K=1536: [Wlo_s x Ahi | Whi x Alo_s | Whi x Ahi])
template <int ACT, bool SPLITOUT>   // ACT: 0=none 1=tanh
__global__ __launch_bounds__(256, 3)
void gemm3_pre(const half_t* __restrict__ Ahi, const half_t* __restrict__ Alo,
               const half_t* __restrict__ Wcat, const float* __restrict__ bias,
               float* __restrict__ Cf, half_t* __restrict__ Chi,
               half_t* __restrict__ Clo, i8_t* __restrict__ C8, int ldc) {
  __shared__ __align__(16) half_t sA[128 * 32];
  __shared__ __align__(16) half_t sB[128 * 32];
  const int tid = threadIdx.x;
  int mt, nt;
  swizzle_tiles(mt, nt);
  const int bm0 = mt * 128, bn0 = nt * 128;
  f32x4 acc[4][4];
#pragma unroll
  for (int i = 0; i < 4; ++i)
#pragma unroll
    for (int j = 0; j < 4; ++j) acc[i][j] = (f32x4){0.f, 0.f, 0.f, 0.f};
#pragma unroll 1
  for (int k0 = 0; k0 < 512; k0 += 32)
    kstep(acc, Ahi, CDIM, k0, Wcat, 1536, k0, sA, sB, bm0, bn0);
#pragma unroll 1
  for (int k0 = 512; k0 < 1024; k0 += 32)
    kstep(acc, Alo, CDIM, k0 - 512, Wcat, 1536, k0, sA, sB, bm0, bn0);
  scale_acc4(acc, ILOSC);
#pragma unroll 1
  for (int k0 = 1024; k0 < 1536; k0 += 32)
    kstep(acc, Ahi, CDIM, k0 - 1024, Wcat, 1536, k0, sA, sB, bm0, bn0);

  const int lane = tid & 63, wave = tid >> 6;
  const int wm = wave >> 1, wn = wave & 1, quad = lane >> 4, lcol = lane & 15;
#pragma unroll
  for (int ni = 0; ni < 4; ++ni) {
    const int col = bn0 + wn * 64 + ni * 16 + lcol;
    const float bv = bias[col];
#pragma unroll
    for (int mi = 0; mi < 4; ++mi) {
      const int row0 = bm0 + wm * 64 + mi * 16 + quad * 4;
#pragma unroll
      for (int r = 0; r < 4; ++r) {
        float v = acc[mi][ni][r] + bv;
        if (ACT == 1) v = tanhf(v);
        if (SPLITOUT) {
          const size_t idx = (size_t)(row0 + r) * ldc + col;
          const half_t hh = hi16(v);
          const float hiF = (float)hh;
          Chi[idx] = hh;
          Clo[idx] = (half_t)((v - hiF) * LOSC);
          const int hq = clamp8((int)rintf(hiF * 128.0f));
          const int lq = clamp8((int)rintf((v - hiF) * 524288.0f));  // 2^19
          C8[(size_t)(row0 + r) * 2048 + col]        = (i8_t)hq;
          C8[(size_t)(row0 + r) * 2048 + 1024 + col] = (i8_t)lq;
        } else {
          Cf[(size_t)(row0 + r) * ldc + col] = v;
        }
      }
    }
  }
}

// ---------- fused gates GEMM (int8 corrections + fp16 main) + LSTM cell ----------
// Phase 1: int8 K=2048 ([hq|lq] x [wloq|whiq]) -> i32 acc (both cross-terms at
//   shared 2^(25-E) scale). Convert in place: acc = ldexpf((float)acc8, E-25).
// Phase 2: fp16 K=1024 (hi x Whi) accumulates on top.
// Epilogue: LDS transpose, +gctx, +rank-4 extra (from dprev), LSTM, h out as
// fp16 hi/lo + int8 [hq|lq], LN-stats atomics.
__global__ __launch_bounds__(256, 3)
void gemm_gates_cell(const half_t* __restrict__ hAhi, const i8_t* __restrict__ hA8,
                     const half_t* __restrict__ Whh16, const i8_t* __restrict__ Whh8,
                     const int* __restrict__ Ebuf,
                     const float* __restrict__ gctx,
                     const float* __restrict__ dprev, const float* __restrict__ b2,
                     const float* __restrict__ Wxt, float* __restrict__ c,
                     half_t* __restrict__ hBhi, half_t* __restrict__ hBlo,
                     i8_t* __restrict__ hB8, float* __restrict__ statsT) {
  __shared__ __align__(16) unsigned char sAraw[8192];
  __shared__ __align__(16) unsigned char sBraw[8192];
  __shared__ __align__(16) float sE[4][16 * 68];
  const int tid = threadIdx.x;
  const int lane = tid & 63;
  const int wave = tid >> 6;
  const int wm = wave >> 1, wn = wave & 1;
  const int quad = lane >> 4;
  const int lcol = lane & 15;
  int mt, nt;
  swizzle_tiles(mt, nt);
  const int bm0 = mt * 128, bn0 = nt * 128;

  // ---- phase 1: int8 corrections, K=2048 bytes, BK=64 ----
  i32x4 acc8[4][4];
#pragma unroll
  for (int i = 0; i < 4; ++i)
#pragma unroll
    for (int j = 0; j < 4; ++j) acc8[i][j] = (i32x4){0, 0, 0, 0};
  {
    const int ar8 = lane >> 2;          // row within 16-row chunk
    const int ab8 = (lane & 3) * 16;    // byte offset within 64B row
#pragma unroll 1
    for (int k0 = 0; k0 < 2048; k0 += 64) {
#pragma unroll
      for (int cc = 0; cc < 2; ++cc) {
        const int chunk = wave + cc * 4;
        async_cp16(hA8 + (size_t)(bm0 + chunk * 16 + ar8) * 2048 + (k0 + ab8),
                   sAraw + chunk * 1024);
        async_cp16(Whh8 + (size_t)(bn0 + chunk * 16 + ar8) * 2048 + (k0 + ab8),
                   sBraw + chunk * 1024);
      }
      asm volatile("s_waitcnt vmcnt(0)" ::: "memory");
      __syncthreads();
      i32x4 ai[4], bi[4];
#pragma unroll
      for (int mi = 0; mi < 4; ++mi)
        ai[mi] = *(const i32x4*)&sAraw[(wm * 64 + mi * 16 + lcol) * 64 + quad * 16];
#pragma unroll
      for (int ni = 0; ni < 4; ++ni)
        bi[ni] = *(const i32x4*)&sBraw[(wn * 64 + ni * 16 + lcol) * 64 + quad * 16];
#pragma unroll
      for (int mi = 0; mi < 4; ++mi)
#pragma unroll
        for (int ni = 0; ni < 4; ++ni)
          acc8[mi][ni] = __builtin_amdgcn_mfma_i32_16x16x64_i8(ai[mi], bi[ni], acc8[mi][ni], 0, 0, 0);
      __syncthreads();
    }
  }
  // convert corrections to f32 (in-place register handoff; acc8 dead after)
  const int E = Ebuf[0];
  f32x4 acc[4][4];
#pragma unroll
  for (int i = 0; i < 4; ++i)
#pragma unroll
    for (int j = 0; j < 4; ++j)
#pragma unroll
      for (int r = 0; r < 4; ++r)
        acc[i][j][r] = ldexpf((float)acc8[i][j][r], E - 25);

  // ---- phase 2: fp16 main (hi x Whi), K=1024, BK=32 ----
#pragma unroll 1
  for (int k0 = 0; k0 < 1024; k0 += 32)
    kstep(acc, hAhi, HDIM, k0, Whh16, 1024, k0,
          (half_t*)sAraw, (half_t*)sBraw, bm0, bn0);

  // ---- epilogue ----
  float* myE = sE[wave];
  const int u = lane & 15;
  const int q = lane >> 4;
  const int j = ((bn0 + wn * 64) >> 2) + u;      // this lane's hidden unit
  const float b20 = b2[0], b21 = b2[1];
  const float4 wx0 = *(const float4*)(Wxt + (size_t)j * 16 + 0);
  const float4 wx1 = *(const float4*)(Wxt + (size_t)j * 16 + 4);
  const float4 wx2 = *(const float4*)(Wxt + (size_t)j * 16 + 8);
  const float4 wx3 = *(const float4*)(Wxt + (size_t)j * 16 + 12);

#pragma unroll
  for (int mi = 0; mi < 4; ++mi) {
#pragma unroll
    for (int ni = 0; ni < 4; ++ni)
#pragma unroll
      for (int r = 0; r < 4; ++r)
        myE[(quad * 4 + r) * 68 + ni * 16 + lcol] = acc[mi][ni][r];
    // same-wave DS ops are in-order: reads below see the writes above
#pragma unroll
    for (int k = 0; k < 4; ++k) {
      const int rr = q + 4 * k;
      const int row = bm0 + wm * 64 + mi * 16 + rr;
      const f32x4 gv = *(const f32x4*)&myE[rr * 68 + u * 4];  // {i,f,g,o} h-part
      const float4 gc = *(const float4*)(gctx + (size_t)row * GDIM + 4 * j);
      const float dx = dprev[2 * row] + b20;
      const float dy = dprev[2 * row + 1] + b21;
      const float nrm = fmaxf(sqrtf(dx * dx + dy * dy), 1e-6f);
      const float ex = dx, ey = dy, ehx = dx / nrm, ehy = dy / nrm;
      const float pi = gv[0] + gc.x + ex*wx0.x + ey*wx0.y + ehx*wx0.z + ehy*wx0.w;
      const float pf = gv[1] + gc.y + ex*wx1.x + ey*wx1.y + ehx*wx1.z + ehy*wx1.w;
      const float pg = gv[2] + gc.z + ex*wx2.x + ey*wx2.y + ehx*wx2.z + ehy*wx2.w;
      const float po = gv[3] + gc.w + ex*wx3.x + ey*wx3.y + ehx*wx3.z + ehy*wx3.w;
      const size_t cidx = (size_t)row * HDIM + j;
      const float cn = sigf(pf) * c[cidx] + sigf(pi) * tanhf(pg);
      c[cidx] = cn;
      const float vh = sigf(po) * tanhf(cn);
      const half_t hh = hi16(vh);
      const float hiF = (float)hh;
      hBhi[cidx] = hh;
      hBlo[cidx] = (half_t)((vh - hiF) * LOSC);
      const int hq = clamp8((int)rintf(hiF * 128.0f));
      const int lq = clamp8((int)rintf((vh - hiF) * 524288.0f));  // 2^19
      hB8[(size_t)row * 2048 + j]        = (i8_t)hq;
      hB8[(size_t)row * 2048 + 1024 + j] = (i8_t)lq;
      float ps = vh, pq = vh * vh;
#pragma unroll
      for (int m = 1; m < 16; m <<= 1) {
        ps += __shfl_xor(ps, m, 64);
        pq += __shfl_xor(pq, m, 64);
      }
      if (u == 0) {
        atomicAdd(&statsT[2 * row], ps);
        atomicAdd(&statsT[2 * row + 1], pq);
      }
    }
  }
}

// ---------- MLP GEMM, 128x64 tile, paired-W kstep (unchanged from r11) ----------
__global__ __launch_bounds__(256, 3)
void gemm_mlp64(const half_t* __restrict__ hBhi, const half_t* __restrict__ hBlo,
                const half_t* __restrict__ W1g, const float* __restrict__ statsT,
                const float* __restrict__ v1, const float* __restrict__ v2,
                const float* __restrict__ W2, float* __restrict__ deltaT) {
  __shared__ __align__(16) half_t sA[128 * 32];
  __shared__ __align__(16) half_t sBl[64 * 32];
  __shared__ __align__(16) half_t sBh[64 * 32];
  const int tid = threadIdx.x;
  const int lane = tid & 63;
  const int wave = tid >> 6;
  const int ar = lane >> 2;
  const int ak = (lane & 3) * 8;
  const int quad = lane >> 4;
  const int lcol = lane & 15;
  int mt, nt;
  swizzle_tiles(mt, nt);
  const int bm0 = mt * 128, bn0 = nt * 64;
  f32x4 accS[2][4], accM[2][4];
#pragma unroll
  for (int i = 0; i < 2; ++i)
#pragma unroll
    for (int jj = 0; jj < 4; ++jj) {
      accS[i][jj] = (f32x4){0.f, 0.f, 0.f, 0.f};
      accM[i][jj] = (f32x4){0.f, 0.f, 0.f, 0.f};
    }

#pragma unroll 1
  for (int k0 = 0; k0 < 1024; k0 += 32) {
#pragma unroll
    for (int cc = 0; cc < 2; ++cc) {
      const int chunk = wave + cc * 4;
      async_cp16(hBhi + (size_t)(bm0 + chunk * 16 + ar) * HDIM + (k0 + ak), sA + chunk * 512);
    }
    async_cp16(W1g + (size_t)(bn0 + wave * 16 + ar) * 2048 + (k0 + ak), sBl + wave * 512);
    async_cp16(W1g + (size_t)(bn0 + wave * 16 + ar) * 2048 + (1024 + k0 + ak), sBh + wave * 512);
    asm volatile("s_waitcnt vmcnt(0)" ::: "memory");
    __syncthreads();
    halfx8 af[2], bl[4], bh[4];
#pragma unroll
    for (int mi = 0; mi < 2; ++mi)
      af[mi] = *(const halfx8*)&sA[(wave * 32 + mi * 16 + lcol) * 32 + quad * 8];
#pragma unroll
    for (int ni = 0; ni < 4; ++ni) {
      bl[ni] = *(const halfx8*)&sBl[(ni * 16 + lcol) * 32 + quad * 8];
      bh[ni] = *(const halfx8*)&sBh[(ni * 16 + lcol) * 32 + quad * 8];
    }
#pragma unroll
    for (int mi = 0; mi < 2; ++mi)
#pragma unroll
      for (int ni = 0; ni < 4; ++ni) {
        accS[mi][ni] = __builtin_amdgcn_mfma_f32_16x16x32_f16(af[mi], bl[ni], accS[mi][ni], 0, 0, 0);
        accM[mi][ni] = __builtin_amdgcn_mfma_f32_16x16x32_f16(af[mi], bh[ni], accM[mi][ni], 0, 0, 0);
      }
    __syncthreads();
  }
#pragma unroll 1
  for (int k0 = 0; k0 < 1024; k0 += 32) {
#pragma unroll
    for (int cc = 0; cc < 2; ++cc) {
      const int chunk = wave + cc * 4;
      async_cp16(hBlo + (size_t)(bm0 + chunk * 16 + ar) * HDIM + (k0 + ak), sA + chunk * 512);
    }
    async_cp16(W1g + (size_t)(bn0 + wave * 16 + ar) * 2048 + (1024 + k0 + ak), sBl + wave * 512);
    asm volatile("s_waitcnt vmcnt(0)" ::: "memory");
    __syncthreads();
    halfx8 af[2], bl[4];
#pragma unroll
    for (int mi = 0; mi < 2; ++mi)
      af[mi] = *(const halfx8*)&sA[(wave * 32 + mi * 16 + lcol) * 32 + quad * 8];
#pragma unroll
    for (int ni = 0; ni < 4; ++ni)
      bl[ni] = *(const halfx8*)&sBl[(ni * 16 + lcol) * 32 + quad * 8];
#pragma unroll
    for (int mi = 0; mi < 2; ++mi)
#pragma unroll
      for (int ni = 0; ni < 4; ++ni)
        accS[mi][ni] = __builtin_amdgcn_mfma_f32_16x16x32_f16(af[mi], bl[ni], accS[mi][ni], 0, 0, 0);
    __syncthreads();
  }
#pragma unroll
  for (int i = 0; i < 2; ++i)
#pragma unroll
    for (int jj = 0; jj < 4; ++jj) accM[i][jj] += accS[i][jj] * ILOSC;

  float w2a[4], w2b[4], v1c[4], v2c[4];
#pragma unroll
  for (int ni = 0; ni < 4; ++ni) {
    const int col = bn0 + ni * 16 + lcol;
    w2a[ni] = W2[col]; w2b[ni] = W2[HDIM + col];
    v1c[ni] = v1[col]; v2c[ni] = v2[col];
  }
#pragma unroll
  for (int mi = 0; mi < 2; ++mi) {
#pragma unroll
    for (int r = 0; r < 4; ++r) {
      const int row = bm0 + wave * 32 + mi * 16 + quad * 4 + r;
      const float S = statsT[2 * row], Q = statsT[2 * row + 1];
      const float mu = S * (1.0f / HDIM);
      const float rs = rsqrtf(Q * (1.0f / HDIM) - mu * mu + 1e-5f);
      float d0 = 0.f, d1 = 0.f;
#pragma unroll
      for (int ni = 0; ni < 4; ++ni) {
        const float g = geluf(rs * (accM[mi][ni][r] - mu * v1c[ni]) + v2c[ni]);
        d0 += g * w2a[ni];
        d1 += g * w2b[ni];
      }
#pragma unroll
      for (int m = 1; m < 16; m <<= 1) {
        d0 += __shfl_xor(d0, m, 64);
        d1 += __shfl_xor(d1, m, 64);
      }
      if (lcol == 0) {
        atomicAdd(&deltaT[2 * row], d0);
        atomicAdd(&deltaT[2 * row + 1], d1);
      }
    }
  }
}

// ---------- trajectory writeback: pos cumsum + out (once per chunk) ----------
__global__ __launch_bounds__(256)
void write_traj(const float* __restrict__ lp, const float* __restrict__ deltaT,
                const float* __restrict__ b2, float* __restrict__ out, int M) {
  const int b = blockIdx.x * 256 + threadIdx.x;
  if (b >= M) return;
  float px = lp[2 * b], py = lp[2 * b + 1];
  const float b20 = b2[0], b21 = b2[1];
  for (int t = 0; t < TSTEP; ++t) {
    px += deltaT[(size_t)t * M * 2 + 2 * b] + b20;
    py += deltaT[(size_t)t * M * 2 + 2 * b + 1] + b21;
    out[((size_t)b * TSTEP + t) * 2 + 0] = px;
    out[((size_t)b * TSTEP + t) * 2 + 1] = py;
  }
}

// ---------- builders ----------
__global__ __launch_bounds__(256)
void cvt_split(const float* __restrict__ s, half_t* __restrict__ dhi,
               half_t* __restrict__ dlo, int n4) {
  int i = blockIdx.x * 256 + threadIdx.x;
  if (i >= n4) return;
  const float4 v = ((const float4*)s)[i];
  halfx4 h = { hi16(v.x), hi16(v.y), hi16(v.z), hi16(v.w) };
  halfx4 l = { lo16(v.x), lo16(v.y), lo16(v.z), lo16(v.w) };
  *(halfx4*)(dhi + (size_t)i * 4) = h;
  *(halfx4*)(dlo + (size_t)i * 4) = l;
}

// global max|W_hh| -> uint bits (monotonic for non-negative floats)
__global__ __launch_bounds__(256)
void wmax_reduce(const float* __restrict__ W, unsigned* __restrict__ mx, int n) {
  float m = 0.f;
  for (int i = blockIdx.x * 256 + threadIdx.x; i < n; i += gridDim.x * 256)
    m = fmaxf(m, fabsf(W[i]));
#pragma unroll
  for (int off = 32; off > 0; off >>= 1)
    m = fmaxf(m, __shfl_down(m, off, 64));
  if ((threadIdx.x & 63) == 0) atomicMax(mx, __float_as_uint(m));
}

__global__ void set_E(const unsigned* __restrict__ mx, int* __restrict__ Ebuf) {
  int e;
  frexpf(__uint_as_float(*mx), &e);
  Ebuf[0] = e - 1;   // floor(log2(max|W|))
}

// Whh16 [4096][1024] fp16 (hi of W_hh, rows interleaved r'=4u+g)
// Whh8  [4096][2048] int8: [0,1024)=wloq (~Wlo*2^(18-E)), [1024,2048)=whiq (~Whi*2^(6-E))
__global__ __launch_bounds__(256)
void build_whh_hyb(const float* __restrict__ Whh, const int* __restrict__ Ebuf,
                   half_t* __restrict__ W16, i8_t* __restrict__ W8) {
  int idx = blockIdx.x * 256 + threadIdx.x;
  if (idx >= GDIM * HDIM) return;
  const int rp = idx >> 10;
  const int k  = idx & 1023;
  const int sr = (rp & 3) * HDIM + (rp >> 2);
  const float w = Whh[(size_t)sr * HDIM + k];
  const half_t whi = (half_t)w;
  const float hiF = (float)whi;
  const float wlo = w - hiF;
  const int E = Ebuf[0];
  W16[(size_t)rp * 1024 + k] = whi;
  W8[(size_t)rp * 2048 + k]        = (i8_t)clamp8((int)rintf(ldexpf(wlo, 18 - E)));
  W8[(size_t)rp * 2048 + 1024 + k] = (i8_t)clamp8((int)rintf(ldexpf(hiF, 6 - E)));
}

// Wxt[j][g*4+c] = W_ih[g*H+j][512+c]  (rank-4 extra weights, fp32)
__global__ __launch_bounds__(256)
void build_wx(const float* __restrict__ Wih, float* __restrict__ Wxt) {
  int rp = blockIdx.x * 256 + threadIdx.x;
  if (rp >= GDIM) return;
  const int jj = rp >> 2, g = rp & 3;
  const int sr = g * HDIM + jj;
  const float4 v = *(const float4*)(Wih + (size_t)sr * 516 + 512);
  *(float4*)(Wxt + (size_t)jj * 16 + g * 4) = v;
}

// Wih_cat [4096][1536] = [lo_s | hi | hi] of W_ih[:, :512], rows interleaved
__global__ __launch_bounds__(256)
void build_wih_cat(const float* __restrict__ Wih, half_t* __restrict__ dst) {
  int idx = blockIdx.x * 256 + threadIdx.x;
  if (idx >= GDIM * 384) return;
  const int rp = idx / 384;
  const int k  = (idx - rp * 384) * 4;
  const int sr = (rp & 3) * HDIM + (rp >> 2);
  const bool lo = (k < 512);
  const int kk = lo ? k : (k < 1024 ? k - 512 : k - 1024);
  const float4 v = *(const float4*)(Wih + (size_t)sr * 516 + kk);
  half_t* d = dst + (size_t)rp * 1536 + k;
  if (lo) { halfx4 o = { lo16(v.x), lo16(v.y), lo16(v.z), lo16(v.w) }; *(halfx4*)d = o; }
  else    { halfx4 o = { hi16(v.x), hi16(v.y), hi16(v.z), hi16(v.w) }; *(halfx4*)d = o; }
}

// bias_i[r'] = b_ih[src] + b_hh[src]
__global__ __launch_bounds__(256)
void build_bias(const float* __restrict__ b_ih, const float* __restrict__ b_hh,
                float* __restrict__ bias_i) {
  int rp = blockIdx.x * 256 + threadIdx.x;
  if (rp >= GDIM) return;
  const int sr = (rp & 3) * HDIM + (rp >> 2);
  bias_i[rp] = b_ih[sr] + b_hh[sr];
}

// W1g2 [1024][2048] = [lo_s | hi] of W1*ln_g; v1=W1g·1; v2=W1·beta + b1
__global__ __launch_bounds__(256)
void build_w1g2(const float* __restrict__ W1, const float* __restrict__ g,
                const float* __restrict__ beta, const float* __restrict__ b1,
                half_t* __restrict__ W1g, float* __restrict__ v1,
                float* __restrict__ v2) {
  const int n = blockIdx.x;
  const int tid = threadIdx.x;
  const int k = tid * 4;
  const float4 w  = *(const float4*)(W1 + (size_t)n * HDIM + k);
  const float4 gg = *(const float4*)(g + k);
  const float4 bb = *(const float4*)(beta + k);
  const float wg0 = w.x*gg.x, wg1 = w.y*gg.y, wg2 = w.z*gg.z, wg3 = w.w*gg.w;
  halfx4 hl = { lo16(wg0), lo16(wg1), lo16(wg2), lo16(wg3) };
  halfx4 hh = { hi16(wg0), hi16(wg1), hi16(wg2), hi16(wg3) };
  *(halfx4*)(W1g + (size_t)n * 2048 + k)        = hl;
  *(halfx4*)(W1g + (size_t)n * 2048 + 1024 + k) = hh;
  float s1 = wg0 + wg1 + wg2 + wg3;
  float s2 = w.x*bb.x + w.y*bb.y + w.z*bb.z + w.w*bb.w;
#pragma unroll
  for (int off = 32; off > 0; off >>= 1) {
    s1 += __shfl_down(s1, off, 64);
    s2 += __shfl_down(s2, off, 64);
  }
  __shared__ float t1[4], t2[4];
  const int wv = tid >> 6, ln = tid & 63;
  if (ln == 0) { t1[wv] = s1; t2[wv] = s2; }
  __syncthreads();
  if (tid == 0) {
    v1[n] = t1[0] + t1[1] + t1[2] + t1[3];
    v2[n] = t2[0] + t2[1] + t2[2] + t2[3] + b1[n];
  }
}

// Wc_cat [1024][1536] = [lo_s | hi | hi] of a [1024][512] fp32 matrix
__global__ __launch_bounds__(128)
void build_wc_cat(const float* __restrict__ W, half_t* __restrict__ dst) {
  const int n = blockIdx.x;
  const int k = threadIdx.x * 4;
  const float4 w = *(const float4*)(W + (size_t)n * CDIM + k);
  halfx4 hl = { lo16(w.x), lo16(w.y), lo16(w.z), lo16(w.w) };
  halfx4 hh = { hi16(w.x), hi16(w.y), hi16(w.z), hi16(w.w) };
  *(halfx4*)(dst + (size_t)n * 1536 + k)        = hl;
  *(halfx4*)(dst + (size_t)n * 1536 + 512 + k)  = hh;
  *(halfx4*)(dst + (size_t)n * 1536 + 1024 + k) = hh;
}

// delta_init = last_delta - b2, so gates t=0 recovers extra from it exactly
__global__ __launch_bounds__(256)
void init_chunk(const float* __restrict__ ld, const float* __restrict__ b2,
                float* __restrict__ delta_init, int M) {
  int b = blockIdx.x * 256 + threadIdx.x;
  if (b >= M) return;
  delta_init[2*b]   = ld[2*b]   - b2[0];
  delta_init[2*b+1] = ld[2*b+1] - b2[1];
}

extern "C" void kernel_launch(void* const* d_in, const int* in_sizes, int n_in,
                              void* d_out, int out_size, void* d_ws, size_t ws_size,
                              hipStream_t stream) {
  const float* context    = (const float*)d_in[0];
  const float* last_pos   = (const float*)d_in[1];
  const float* last_delta = (const float*)d_in[2];
  const float* Wh   = (const float*)d_in[3];
  const float* bh   = (const float*)d_in[4];
  const float* Wc   = (const float*)d_in[5];
  const float* bc   = (const float*)d_in[6];
  const float* W_ih = (const float*)d_in[7];
  const float* b_ih = (const float*)d_in[8];
  const float* W_hh = (const float*)d_in[9];
  const float* b_hh = (const float*)d_in[10];
  const float* ln_g = (const float*)d_in[11];
  const float* ln_b = (const float*)d_in[12];
  const float* W1   = (const float*)d_in[13];
  const float* b1   = (const float*)d_in[14];
  const float* W2   = (const float*)d_in[15];
  const float* b2   = (const float*)d_in[16];
  float* out = (float*)d_out;

  // ---- workspace plan ----
  const size_t stat_bytes =
      (size_t)GDIM * 1024 * 2 +        // Whh16
      (size_t)GDIM * 2048 +            // Whh8
      (size_t)GDIM * 1536 * 2 +        // Wih_cat
      (size_t)HDIM * 2048 * 2 +        // W1g2
      2 * (size_t)HDIM * 1536 * 2 +    // Wh_cat + Wc_cat
      (size_t)HDIM * 16 * 4 + (size_t)GDIM * 4 + 2 * (size_t)HDIM * 4 + 32768;
  int NC = 0;
  for (int nc : {2, 4, 8, 16}) {
    const size_t M = BATCH / nc;
    const size_t chunk_bytes = 4 * M * HDIM * 2 +       // h hi/lo x2
                               2 * M * 2048 +            // h8 x2
                               2 * M * CDIM * 2 +        // ctx hi/lo
                               M * HDIM * 4 +            // c
                               (size_t)M * GDIM * 4 +    // gctx
                               M * 2 * 4 +               // dinit
                               2 * (size_t)TSTEP * M * 2 * 4 + 32768;
    if (stat_bytes + chunk_bytes <= ws_size) { NC = nc; break; }
  }
  if (NC == 0) return;
  const int M = BATCH / NC;

  char* w = (char*)d_ws;
  auto take = [&](size_t bytes) {
    char* p = w;
    w += (bytes + 255) & ~(size_t)255;
    return p;
  };
  half_t* Whh16   = (half_t*)take((size_t)GDIM * 1024 * 2);
  i8_t*   Whh8    = (i8_t*)take((size_t)GDIM * 2048);
  half_t* Wih_cat = (half_t*)take((size_t)GDIM * 1536 * 2);
  half_t* W1g2    = (half_t*)take((size_t)HDIM * 2048 * 2);
  half_t* Wh_cat  = (half_t*)take((size_t)HDIM * 1536 * 2);
  half_t* Wc_cat  = (half_t*)take((size_t)HDIM * 1536 * 2);
  float*  Wxt     = (float*)take((size_t)HDIM * 16 * 4);
  float*  bias_i  = (float*)take((size_t)GDIM * 4);
  float*  v1      = (float*)take((size_t)HDIM * 4);
  float*  v2      = (float*)take((size_t)HDIM * 4);
  unsigned* mx    = (unsigned*)take(256);
  int*    Ebuf    = (int*)take(256);
  half_t* h0hi    = (half_t*)take((size_t)M * HDIM * 2);
  half_t* h0lo    = (half_t*)take((size_t)M * HDIM * 2);
  half_t* h1hi    = (half_t*)take((size_t)M * HDIM * 2);
  half_t* h1lo    = (half_t*)take((size_t)M * HDIM * 2);
  i8_t*   h08     = (i8_t*)take((size_t)M * 2048);
  i8_t*   h18     = (i8_t*)take((size_t)M * 2048);
  half_t* ctx_hi  = (half_t*)take((size_t)M * CDIM * 2);
  half_t* ctx_lo  = (half_t*)take((size_t)M * CDIM * 2);
  float*  c_f     = (float*)take((size_t)M * HDIM * 4);
  float*  gctx    = (float*)take((size_t)M * GDIM * 4);
  float*  dinit   = (float*)take((size_t)M * 2 * 4);
  const size_t sd_bytes = 2 * (size_t)TSTEP * M * 2 * 4;
  float*  statsAll = (float*)take(sd_bytes);            // [60][M][2] stats
  float*  deltaAll = statsAll + (size_t)TSTEP * M * 2;  // [60][M][2] delta

  // static builders (once)
  hipMemsetAsync(mx, 0, 4, stream);
  wmax_reduce<<<256, 256, 0, stream>>>(W_hh, mx, GDIM * HDIM);
  set_E<<<1, 1, 0, stream>>>(mx, Ebuf);
  build_whh_hyb<<<(GDIM * HDIM + 255) / 256, 256, 0, stream>>>(W_hh, Ebuf, Whh16, Whh8);
  build_wx<<<(GDIM + 255) / 256, 256, 0, stream>>>(W_ih, Wxt);
  build_wih_cat<<<(GDIM * 384 + 255) / 256, 256, 0, stream>>>(W_ih, Wih_cat);
  build_bias<<<(GDIM + 255) / 256, 256, 0, stream>>>(b_ih, b_hh, bias_i);
  build_w1g2<<<HDIM, 256, 0, stream>>>(W1, ln_g, ln_b, b1, W1g2, v1, v2);
  build_wc_cat<<<HDIM, 128, 0, stream>>>(Wh, Wh_cat);
  build_wc_cat<<<HDIM, 128, 0, stream>>>(Wc, Wc_cat);

  const dim3 blk(256);
  for (int chunk = 0; chunk < NC; ++chunk) {
    const size_t base = (size_t)chunk * M;
    hipMemsetAsync(statsAll, 0, sd_bytes, stream);
    cvt_split<<<(M * CDIM / 4 + 255) / 256, 256, 0, stream>>>(
        context + base * CDIM, ctx_hi, ctx_lo, M * CDIM / 4);
    gemm3_pre<1, true ><<<dim3(M/128, HDIM/128), blk, 0, stream>>>(
        ctx_hi, ctx_lo, Wh_cat, bh, nullptr, h0hi, h0lo, h08, HDIM);
    gemm3_pre<1, false><<<dim3(M/128, HDIM/128), blk, 0, stream>>>(
        ctx_hi, ctx_lo, Wc_cat, bc, c_f, nullptr, nullptr, nullptr, HDIM);
    gemm3_pre<0, false><<<dim3(M/128, GDIM/128), blk, 0, stream>>>(
        ctx_hi, ctx_lo, Wih_cat, bias_i, gctx, nullptr, nullptr, nullptr, GDIM);
    init_chunk<<<(M + 255) / 256, 256, 0, stream>>>(
        last_delta + base * 2, b2, dinit, M);

    const half_t* hAhi = h0hi; const half_t* hAlo = h0lo;
    const i8_t* hA8 = h08;
    half_t* hBhi = h1hi; half_t* hBlo = h1lo;
    i8_t* hB8 = h18;
    for (int t = 0; t < TSTEP; ++t) {
      const float* dprev = (t == 0) ? dinit : deltaAll + (size_t)(t - 1) * M * 2;
      gemm_gates_cell<<<dim3(M/128, GDIM/128), blk, 0, stream>>>(
          hAhi, hA8, Whh16, Whh8, Ebuf, gctx, dprev, b2, Wxt, c_f,
          hBhi, hBlo, hB8, statsAll + (size_t)t * M * 2);
      gemm_mlp64<<<dim3(M/128, HDIM/64), blk, 0, stream>>>(
          hBhi, hBlo, W1g2, statsAll + (size_t)t * M * 2, v1, v2, W2,
          deltaAll + (size_t)t * M * 2);
      half_t* th = hBhi; hBhi = (half_t*)hAhi; hAhi = th;
      half_t* tl = hBlo; hBlo = (half_t*)hAlo; hAlo = tl;
      i8_t* t8 = hB8; hB8 = (i8_t*)hA8; hA8 = t8;
    }
    write_traj<<<(M + 255) / 256, 256, 0, stream>>>(
        last_pos + base * 2, deltaAll, b2, out + base * TSTEP * 2, M);
  }
  (void)in_sizes; (void)n_in; (void)out_size;
}

// Round 13
// 36323.907 us; speedup vs baseline: 1.3417x; 1.0680x over previous
//
#include <hip/hip_runtime.h>
#include <math.h>

constexpr int BATCH = 16384;
constexpr int CDIM  = 512;
constexpr int HDIM  = 1024;
constexpr int GDIM  = 4096;   // 4*H
constexpr int TSTEP = 60;
// split-fp16: x = hi + lo (|lo| <= 2^-12). Hybrid GEMMs (gates & MLP):
//   main:        hi x Whi   fp16 MFMA, f32 acc (products exact in f32)
//   corrections: hi x Wlo + lo x Whi  as ONE int8 GEMM (2x rate), both
//   cross-terms quantized to a shared 2^(25-E) fixed-point scale.
constexpr float LOSC  = 2048.0f;       // 2^11 (fp16 lo limb pre-scale)
constexpr float ILOSC = 1.0f / 2048.0f;

typedef _Float16 half_t;
typedef _Float16 halfx8 __attribute__((ext_vector_type(8)));
typedef _Float16 halfx4 __attribute__((ext_vector_type(4)));
typedef float    f32x4  __attribute__((ext_vector_type(4)));
typedef int      i32x4  __attribute__((ext_vector_type(4)));
typedef signed char i8_t;

__device__ __forceinline__ void async_cp16(const void* g, void* l) {
  __builtin_amdgcn_global_load_lds((__attribute__((address_space(1))) void*)g,
                                   (__attribute__((address_space(3))) void*)l,
                                   16, 0, 0);
}

__device__ __forceinline__ half_t hi16(float x) { return (half_t)x; }
__device__ __forceinline__ half_t lo16(float x) {
  return (half_t)((x - (float)((half_t)x)) * LOSC);
}
__device__ __forceinline__ int clamp8(int v) {
  return v > 127 ? 127 : (v < -127 ? -127 : v);
}
__device__ __forceinline__ float sigf(float x) { return 1.0f / (1.0f + expf(-x)); }
__device__ __forceinline__ float geluf(float v) {
  return 0.5f * v * (1.0f + erff(v * 0.70710678118f));
}

// XCD-aware tile swizzle (r8: neutral but harmless; kept).
__device__ __forceinline__ void swizzle_tiles(int& mt, int& nt) {
  const int gx = gridDim.x, gy = gridDim.y;
  if (gy & 7) { mt = blockIdx.x; nt = blockIdx.y; return; }
  const int lin = blockIdx.y * gx + blockIdx.x;
  const int xcd = lin & 7;
  const int slot = lin >> 3;
  const int npx = gy >> 3;
  nt = xcd * npx + (slot % npx);
  mt = slot / npx;
}

// ---------- one BK=32 fp16 step, 128x128 tile ----------
__device__ __forceinline__ void kstep(f32x4 (&acc)[4][4],
    const half_t* __restrict__ A, size_t lda, int krel,
    const half_t* __restrict__ W, size_t ldw, int kw,
    half_t* sA, half_t* sB, int bm0, int bn0) {
  const int tid  = threadIdx.x;
  const int lane = tid & 63;
  const int wave = tid >> 6;
  const int wm = wave >> 1, wn = wave & 1;
  const int ar = lane >> 2;
  const int ak = (lane & 3) * 8;
  const int quad = lane >> 4;
  const int lcol = lane & 15;
#pragma unroll
  for (int cc = 0; cc < 2; ++cc) {
    const int chunk = wave + cc * 4;
    async_cp16(A + (size_t)(bm0 + chunk * 16 + ar) * lda + (krel + ak), sA + chunk * 512);
    async_cp16(W + (size_t)(bn0 + chunk * 16 + ar) * ldw + (kw + ak), sB + chunk * 512);
  }
  asm volatile("s_waitcnt vmcnt(0)" ::: "memory");
  __syncthreads();
  halfx8 af[4], bfr[4];
#pragma unroll
  for (int mi = 0; mi < 4; ++mi)
    af[mi] = *(const halfx8*)&sA[(wm * 64 + mi * 16 + lcol) * 32 + quad * 8];
#pragma unroll
  for (int ni = 0; ni < 4; ++ni)
    bfr[ni] = *(const halfx8*)&sB[(wn * 64 + ni * 16 + lcol) * 32 + quad * 8];
#pragma unroll
  for (int mi = 0; mi < 4; ++mi)
#pragma unroll
    for (int ni = 0; ni < 4; ++ni)
      acc[mi][ni] = __builtin_amdgcn_mfma_f32_16x16x32_f16(af[mi], bfr[ni], acc[mi][ni], 0, 0, 0);
  __syncthreads();
}

__device__ __forceinline__ void scale_acc4(f32x4 (&acc)[4][4], float s) {
#pragma unroll
  for (int i = 0; i < 4; ++i)
#pragma unroll
    for (int j = 0; j < 4; ++j) acc[i][j] *= s;
}

// ---------- preamble split GEMM (K=1536: [Wlo_s x Ahi | Whi x Alo_s | Whi x Ahi])
template <int ACT, bool SPLITOUT>   // ACT: 0=none 1=tanh
__global__ __launch_bounds__(256, 3)
void gemm3_pre(const half_t* __restrict__ Ahi, const half_t* __restrict__ Alo,
               const half_t* __restrict__ Wcat, const float* __restrict__ bias,
               float* __restrict__ Cf, half_t* __restrict__ Chi,
               i8_t* __restrict__ C8, int ldc) {
  __shared__ __align__(16) half_t sA[128 * 32];
  __shared__ __align__(16) half_t sB[128 * 32];
  const int tid = threadIdx.x;
  int mt, nt;
  swizzle_tiles(mt, nt);
  const int bm0 = mt * 128, bn0 = nt * 128;
  f32x4 acc[4][4];
#pragma unroll
  for (int i = 0; i < 4; ++i)
#pragma unroll
    for (int j = 0; j < 4; ++j) acc[i][j] = (f32x4){0.f, 0.f, 0.f, 0.f};
#pragma unroll 1
  for (int k0 = 0; k0 < 512; k0 += 32)
    kstep(acc, Ahi, CDIM, k0, Wcat, 1536, k0, sA, sB, bm0, bn0);
#pragma unroll 1
  for (int k0 = 512; k0 < 1024; k0 += 32)
    kstep(acc, Alo, CDIM, k0 - 512, Wcat, 1536, k0, sA, sB, bm0, bn0);
  scale_acc4(acc, ILOSC);
#pragma unroll 1
  for (int k0 = 1024; k0 < 1536; k0 += 32)
    kstep(acc, Ahi, CDIM, k0 - 1024, Wcat, 1536, k0, sA, sB, bm0, bn0);

  const int lane = tid & 63, wave = tid >> 6;
  const int wm = wave >> 1, wn = wave & 1, quad = lane >> 4, lcol = lane & 15;
#pragma unroll
  for (int ni = 0; ni < 4; ++ni) {
    const int col = bn0 + wn * 64 + ni * 16 + lcol;
    const float bv = bias[col];
#pragma unroll
    for (int mi = 0; mi < 4; ++mi) {
      const int row0 = bm0 + wm * 64 + mi * 16 + quad * 4;
#pragma unroll
      for (int r = 0; r < 4; ++r) {
        float v = acc[mi][ni][r] + bv;
        if (ACT == 1) v = tanhf(v);
        if (SPLITOUT) {
          const half_t hh = hi16(v);
          const float hiF = (float)hh;
          Chi[(size_t)(row0 + r) * ldc + col] = hh;
          const int hq = clamp8((int)rintf(hiF * 128.0f));
          const int lq = clamp8((int)rintf((v - hiF) * 524288.0f));  // 2^19
          C8[(size_t)(row0 + r) * 2048 + col]        = (i8_t)hq;
          C8[(size_t)(row0 + r) * 2048 + 1024 + col] = (i8_t)lq;
        } else {
          Cf[(size_t)(row0 + r) * ldc + col] = v;
        }
      }
    }
  }
}

// ---------- fused gates GEMM (int8 corrections + fp16 main) + LSTM cell ----------
__global__ __launch_bounds__(256, 3)
void gemm_gates_cell(const half_t* __restrict__ hAhi, const i8_t* __restrict__ hA8,
                     const half_t* __restrict__ Whh16, const i8_t* __restrict__ Whh8,
                     const int* __restrict__ Ebuf,
                     const float* __restrict__ gctx,
                     const float* __restrict__ dprev, const float* __restrict__ b2,
                     const float* __restrict__ Wxt, float* __restrict__ c,
                     half_t* __restrict__ hBhi, i8_t* __restrict__ hB8,
                     float* __restrict__ statsT) {
  __shared__ __align__(16) unsigned char sAraw[8192];
  __shared__ __align__(16) unsigned char sBraw[8192];
  __shared__ __align__(16) float sE[4][16 * 68];
  const int tid = threadIdx.x;
  const int lane = tid & 63;
  const int wave = tid >> 6;
  const int wm = wave >> 1, wn = wave & 1;
  const int quad = lane >> 4;
  const int lcol = lane & 15;
  int mt, nt;
  swizzle_tiles(mt, nt);
  const int bm0 = mt * 128, bn0 = nt * 128;

  // ---- phase 1: int8 corrections, K=2048 bytes, BK=64 ----
  i32x4 acc8[4][4];
#pragma unroll
  for (int i = 0; i < 4; ++i)
#pragma unroll
    for (int j = 0; j < 4; ++j) acc8[i][j] = (i32x4){0, 0, 0, 0};
  {
    const int ar8 = lane >> 2;
    const int ab8 = (lane & 3) * 16;
#pragma unroll 1
    for (int k0 = 0; k0 < 2048; k0 += 64) {
#pragma unroll
      for (int cc = 0; cc < 2; ++cc) {
        const int chunk = wave + cc * 4;
        async_cp16(hA8 + (size_t)(bm0 + chunk * 16 + ar8) * 2048 + (k0 + ab8),
                   sAraw + chunk * 1024);
        async_cp16(Whh8 + (size_t)(bn0 + chunk * 16 + ar8) * 2048 + (k0 + ab8),
                   sBraw + chunk * 1024);
      }
      asm volatile("s_waitcnt vmcnt(0)" ::: "memory");
      __syncthreads();
      i32x4 ai[4], bi[4];
#pragma unroll
      for (int mi = 0; mi < 4; ++mi)
        ai[mi] = *(const i32x4*)&sAraw[(wm * 64 + mi * 16 + lcol) * 64 + quad * 16];
#pragma unroll
      for (int ni = 0; ni < 4; ++ni)
        bi[ni] = *(const i32x4*)&sBraw[(wn * 64 + ni * 16 + lcol) * 64 + quad * 16];
#pragma unroll
      for (int mi = 0; mi < 4; ++mi)
#pragma unroll
        for (int ni = 0; ni < 4; ++ni)
          acc8[mi][ni] = __builtin_amdgcn_mfma_i32_16x16x64_i8(ai[mi], bi[ni], acc8[mi][ni], 0, 0, 0);
      __syncthreads();
    }
  }
  const int E = Ebuf[0];
  f32x4 acc[4][4];
#pragma unroll
  for (int i = 0; i < 4; ++i)
#pragma unroll
    for (int j = 0; j < 4; ++j)
#pragma unroll
      for (int r = 0; r < 4; ++r)
        acc[i][j][r] = ldexpf((float)acc8[i][j][r], E - 25);

  // ---- phase 2: fp16 main (hi x Whi), K=1024, BK=32 ----
#pragma unroll 1
  for (int k0 = 0; k0 < 1024; k0 += 32)
    kstep(acc, hAhi, HDIM, k0, Whh16, 1024, k0,
          (half_t*)sAraw, (half_t*)sBraw, bm0, bn0);

  // ---- epilogue ----
  float* myE = sE[wave];
  const int u = lane & 15;
  const int q = lane >> 4;
  const int j = ((bn0 + wn * 64) >> 2) + u;
  const float b20 = b2[0], b21 = b2[1];
  const float4 wx0 = *(const float4*)(Wxt + (size_t)j * 16 + 0);
  const float4 wx1 = *(const float4*)(Wxt + (size_t)j * 16 + 4);
  const float4 wx2 = *(const float4*)(Wxt + (size_t)j * 16 + 8);
  const float4 wx3 = *(const float4*)(Wxt + (size_t)j * 16 + 12);

#pragma unroll
  for (int mi = 0; mi < 4; ++mi) {
#pragma unroll
    for (int ni = 0; ni < 4; ++ni)
#pragma unroll
      for (int r = 0; r < 4; ++r)
        myE[(quad * 4 + r) * 68 + ni * 16 + lcol] = acc[mi][ni][r];
    // same-wave DS ops are in-order: reads below see the writes above
#pragma unroll
    for (int k = 0; k < 4; ++k) {
      const int rr = q + 4 * k;
      const int row = bm0 + wm * 64 + mi * 16 + rr;
      const f32x4 gv = *(const f32x4*)&myE[rr * 68 + u * 4];  // {i,f,g,o} h-part
      const float4 gc = *(const float4*)(gctx + (size_t)row * GDIM + 4 * j);
      const float dx = dprev[2 * row] + b20;
      const float dy = dprev[2 * row + 1] + b21;
      const float nrm = fmaxf(sqrtf(dx * dx + dy * dy), 1e-6f);
      const float ex = dx, ey = dy, ehx = dx / nrm, ehy = dy / nrm;
      const float pi = gv[0] + gc.x + ex*wx0.x + ey*wx0.y + ehx*wx0.z + ehy*wx0.w;
      const float pf = gv[1] + gc.y + ex*wx1.x + ey*wx1.y + ehx*wx1.z + ehy*wx1.w;
      const float pg = gv[2] + gc.z + ex*wx2.x + ey*wx2.y + ehx*wx2.z + ehy*wx2.w;
      const float po = gv[3] + gc.w + ex*wx3.x + ey*wx3.y + ehx*wx3.z + ehy*wx3.w;
      const size_t cidx = (size_t)row * HDIM + j;
      const float cn = sigf(pf) * c[cidx] + sigf(pi) * tanhf(pg);
      c[cidx] = cn;
      const float vh = sigf(po) * tanhf(cn);
      const half_t hh = hi16(vh);
      const float hiF = (float)hh;
      hBhi[cidx] = hh;
      const int hq = clamp8((int)rintf(hiF * 128.0f));
      const int lq = clamp8((int)rintf((vh - hiF) * 524288.0f));  // 2^19
      hB8[(size_t)row * 2048 + j]        = (i8_t)hq;
      hB8[(size_t)row * 2048 + 1024 + j] = (i8_t)lq;
      float ps = vh, pq = vh * vh;
#pragma unroll
      for (int m = 1; m < 16; m <<= 1) {
        ps += __shfl_xor(ps, m, 64);
        pq += __shfl_xor(pq, m, 64);
      }
      if (u == 0) {
        atomicAdd(&statsT[2 * row], ps);
        atomicAdd(&statsT[2 * row + 1], pq);
      }
    }
  }
}

// ---------- MLP GEMM, 128x64 tile, int8 corrections + fp16 main ----------
// Phase 1: int8 K=2048 ([hq|lq] x [w1loq|w1hiq]) -> i32 -> f32 at 2^(E1-25).
// Phase 2: fp16 K=1024 (h_hi x W1hi) on top. Epilogue: LN fold, gelu, W2-dot.
__global__ __launch_bounds__(256, 3)
void gemm_mlp64(const half_t* __restrict__ hBhi, const i8_t* __restrict__ hB8,
                const half_t* __restrict__ W1hi, const i8_t* __restrict__ W18,
                const int* __restrict__ Ebuf, const float* __restrict__ statsT,
                const float* __restrict__ v1, const float* __restrict__ v2,
                const float* __restrict__ W2, float* __restrict__ deltaT) {
  __shared__ __align__(16) unsigned char sAraw[8192];
  __shared__ __align__(16) unsigned char sBraw[4096];
  const int tid = threadIdx.x;
  const int lane = tid & 63;
  const int wave = tid >> 6;
  const int quad = lane >> 4;
  const int lcol = lane & 15;
  int mt, nt;
  swizzle_tiles(mt, nt);
  const int bm0 = mt * 128, bn0 = nt * 64;

  // ---- phase 1: int8 corrections ----
  i32x4 acc8[2][4];
#pragma unroll
  for (int i = 0; i < 2; ++i)
#pragma unroll
    for (int jj = 0; jj < 4; ++jj) acc8[i][jj] = (i32x4){0, 0, 0, 0};
  {
    const int ar8 = lane >> 2;
    const int ab8 = (lane & 3) * 16;
#pragma unroll 1
    for (int k0 = 0; k0 < 2048; k0 += 64) {
#pragma unroll
      for (int cc = 0; cc < 2; ++cc) {
        const int chunk = wave + cc * 4;
        async_cp16(hB8 + (size_t)(bm0 + chunk * 16 + ar8) * 2048 + (k0 + ab8),
                   sAraw + chunk * 1024);
      }
      async_cp16(W18 + (size_t)(bn0 + wave * 16 + ar8) * 2048 + (k0 + ab8),
                 sBraw + wave * 1024);
      asm volatile("s_waitcnt vmcnt(0)" ::: "memory");
      __syncthreads();
      i32x4 ai[2], bi[4];
#pragma unroll
      for (int mi = 0; mi < 2; ++mi)
        ai[mi] = *(const i32x4*)&sAraw[(wave * 32 + mi * 16 + lcol) * 64 + quad * 16];
#pragma unroll
      for (int ni = 0; ni < 4; ++ni)
        bi[ni] = *(const i32x4*)&sBraw[(ni * 16 + lcol) * 64 + quad * 16];
#pragma unroll
      for (int mi = 0; mi < 2; ++mi)
#pragma unroll
        for (int ni = 0; ni < 4; ++ni)
          acc8[mi][ni] = __builtin_amdgcn_mfma_i32_16x16x64_i8(ai[mi], bi[ni], acc8[mi][ni], 0, 0, 0);
      __syncthreads();
    }
  }
  const int E1 = Ebuf[1];
  f32x4 accM[2][4];
#pragma unroll
  for (int i = 0; i < 2; ++i)
#pragma unroll
    for (int jj = 0; jj < 4; ++jj)
#pragma unroll
      for (int r = 0; r < 4; ++r)
        accM[i][jj][r] = ldexpf((float)acc8[i][jj][r], E1 - 25);

  // ---- phase 2: fp16 main (h_hi x W1hi), K=1024, BK=32 ----
  {
    half_t* sA = (half_t*)sAraw;
    half_t* sB = (half_t*)sBraw;
    const int ar = lane >> 2;
    const int ak = (lane & 3) * 8;
#pragma unroll 1
    for (int k0 = 0; k0 < 1024; k0 += 32) {
#pragma unroll
      for (int cc = 0; cc < 2; ++cc) {
        const int chunk = wave + cc * 4;
        async_cp16(hBhi + (size_t)(bm0 + chunk * 16 + ar) * HDIM + (k0 + ak), sA + chunk * 512);
      }
      async_cp16(W1hi + (size_t)(bn0 + wave * 16 + ar) * HDIM + (k0 + ak), sB + wave * 512);
      asm volatile("s_waitcnt vmcnt(0)" ::: "memory");
      __syncthreads();
      halfx8 af[2], bfr[4];
#pragma unroll
      for (int mi = 0; mi < 2; ++mi)
        af[mi] = *(const halfx8*)&sA[(wave * 32 + mi * 16 + lcol) * 32 + quad * 8];
#pragma unroll
      for (int ni = 0; ni < 4; ++ni)
        bfr[ni] = *(const halfx8*)&sB[(ni * 16 + lcol) * 32 + quad * 8];
#pragma unroll
      for (int mi = 0; mi < 2; ++mi)
#pragma unroll
        for (int ni = 0; ni < 4; ++ni)
          accM[mi][ni] = __builtin_amdgcn_mfma_f32_16x16x32_f16(af[mi], bfr[ni], accM[mi][ni], 0, 0, 0);
      __syncthreads();
    }
  }

  float w2a[4], w2b[4], v1c[4], v2c[4];
#pragma unroll
  for (int ni = 0; ni < 4; ++ni) {
    const int col = bn0 + ni * 16 + lcol;
    w2a[ni] = W2[col]; w2b[ni] = W2[HDIM + col];
    v1c[ni] = v1[col]; v2c[ni] = v2[col];
  }
#pragma unroll
  for (int mi = 0; mi < 2; ++mi) {
#pragma unroll
    for (int r = 0; r < 4; ++r) {
      const int row = bm0 + wave * 32 + mi * 16 + quad * 4 + r;
      const float S = statsT[2 * row], Q = statsT[2 * row + 1];
      const float mu = S * (1.0f / HDIM);
      const float rs = rsqrtf(Q * (1.0f / HDIM) - mu * mu + 1e-5f);
      float d0 = 0.f, d1 = 0.f;
#pragma unroll
      for (int ni = 0; ni < 4; ++ni) {
        const float g = geluf(rs * (accM[mi][ni][r] - mu * v1c[ni]) + v2c[ni]);
        d0 += g * w2a[ni];
        d1 += g * w2b[ni];
      }
#pragma unroll
      for (int m = 1; m < 16; m <<= 1) {
        d0 += __shfl_xor(d0, m, 64);
        d1 += __shfl_xor(d1, m, 64);
      }
      if (lcol == 0) {
        atomicAdd(&deltaT[2 * row], d0);
        atomicAdd(&deltaT[2 * row + 1], d1);
      }
    }
  }
}

// ---------- trajectory writeback: pos cumsum + out (once per chunk) ----------
__global__ __launch_bounds__(256)
void write_traj(const float* __restrict__ lp, const float* __restrict__ deltaT,
                const float* __restrict__ b2, float* __restrict__ out, int M) {
  const int b = blockIdx.x * 256 + threadIdx.x;
  if (b >= M) return;
  float px = lp[2 * b], py = lp[2 * b + 1];
  const float b20 = b2[0], b21 = b2[1];
  for (int t = 0; t < TSTEP; ++t) {
    px += deltaT[(size_t)t * M * 2 + 2 * b] + b20;
    py += deltaT[(size_t)t * M * 2 + 2 * b + 1] + b21;
    out[((size_t)b * TSTEP + t) * 2 + 0] = px;
    out[((size_t)b * TSTEP + t) * 2 + 1] = py;
  }
}

// ---------- builders ----------
__global__ __launch_bounds__(256)
void cvt_split(const float* __restrict__ s, half_t* __restrict__ dhi,
               half_t* __restrict__ dlo, int n4) {
  int i = blockIdx.x * 256 + threadIdx.x;
  if (i >= n4) return;
  const float4 v = ((const float4*)s)[i];
  halfx4 h = { hi16(v.x), hi16(v.y), hi16(v.z), hi16(v.w) };
  halfx4 l = { lo16(v.x), lo16(v.y), lo16(v.z), lo16(v.w) };
  *(halfx4*)(dhi + (size_t)i * 4) = h;
  *(halfx4*)(dlo + (size_t)i * 4) = l;
}

// global max|W_hh| and max|W1*g| -> uint bits (monotonic for non-neg floats)
__global__ __launch_bounds__(256)
void wmax_reduce(const float* __restrict__ W, unsigned* __restrict__ mx, int n) {
  float m = 0.f;
  for (int i = blockIdx.x * 256 + threadIdx.x; i < n; i += gridDim.x * 256)
    m = fmaxf(m, fabsf(W[i]));
#pragma unroll
  for (int off = 32; off > 0; off >>= 1)
    m = fmaxf(m, __shfl_down(m, off, 64));
  if ((threadIdx.x & 63) == 0) atomicMax(mx, __float_as_uint(m));
}

__global__ __launch_bounds__(256)
void wmax_w1g(const float* __restrict__ W1, const float* __restrict__ g,
              unsigned* __restrict__ mx) {
  float m = 0.f;
  for (int i = blockIdx.x * 256 + threadIdx.x; i < HDIM * HDIM; i += gridDim.x * 256)
    m = fmaxf(m, fabsf(W1[i] * g[i & 1023]));
#pragma unroll
  for (int off = 32; off > 0; off >>= 1)
    m = fmaxf(m, __shfl_down(m, off, 64));
  if ((threadIdx.x & 63) == 0) atomicMax(mx, __float_as_uint(m));
}

__global__ void set_E(const unsigned* __restrict__ mx, int* __restrict__ Ebuf) {
  int e;
  frexpf(__uint_as_float(mx[0]), &e);
  Ebuf[0] = e - 1;
  frexpf(__uint_as_float(mx[1]), &e);
  Ebuf[1] = e - 1;
}

// Whh16 [4096][1024] fp16 (hi of W_hh, rows interleaved r'=4u+g)
// Whh8  [4096][2048] int8: [0,1024)=wloq (~Wlo*2^(18-E)), [1024,2048)=whiq (~Whi*2^(6-E))
__global__ __launch_bounds__(256)
void build_whh_hyb(const float* __restrict__ Whh, const int* __restrict__ Ebuf,
                   half_t* __restrict__ W16, i8_t* __restrict__ W8) {
  int idx = blockIdx.x * 256 + threadIdx.x;
  if (idx >= GDIM * HDIM) return;
  const int rp = idx >> 10;
  const int k  = idx & 1023;
  const int sr = (rp & 3) * HDIM + (rp >> 2);
  const float w = Whh[(size_t)sr * HDIM + k];
  const half_t whi = (half_t)w;
  const float hiF = (float)whi;
  const float wlo = w - hiF;
  const int E = Ebuf[0];
  W16[(size_t)rp * 1024 + k] = whi;
  W8[(size_t)rp * 2048 + k]        = (i8_t)clamp8((int)rintf(ldexpf(wlo, 18 - E)));
  W8[(size_t)rp * 2048 + 1024 + k] = (i8_t)clamp8((int)rintf(ldexpf(hiF, 6 - E)));
}

// W1hi [1024][1024] fp16 hi of W1*ln_g; W18 [1024][2048] = [w1loq | w1hiq];
// v1[n]=sum(W1g row); v2[n]=W1[n]·beta + b1[n]
__global__ __launch_bounds__(256)
void build_w1_hyb(const float* __restrict__ W1, const float* __restrict__ g,
                  const float* __restrict__ beta, const float* __restrict__ b1,
                  const int* __restrict__ Ebuf, half_t* __restrict__ W1hi,
                  i8_t* __restrict__ W18, float* __restrict__ v1,
                  float* __restrict__ v2) {
  const int n = blockIdx.x;
  const int tid = threadIdx.x;
  const int k = tid * 4;
  const int E1 = Ebuf[1];
  const float4 w  = *(const float4*)(W1 + (size_t)n * HDIM + k);
  const float4 gg = *(const float4*)(g + k);
  const float4 bb = *(const float4*)(beta + k);
  float wg[4] = { w.x*gg.x, w.y*gg.y, w.z*gg.z, w.w*gg.w };
  halfx4 hh;
  float s1 = 0.f;
#pragma unroll
  for (int u = 0; u < 4; ++u) {
    const half_t h = (half_t)wg[u];
    hh[u] = h;
    const float hiF = (float)h;
    const float lo = wg[u] - hiF;
    W18[(size_t)n * 2048 + k + u]        = (i8_t)clamp8((int)rintf(ldexpf(lo, 18 - E1)));
    W18[(size_t)n * 2048 + 1024 + k + u] = (i8_t)clamp8((int)rintf(ldexpf(hiF, 6 - E1)));
    s1 += wg[u];
  }
  *(halfx4*)(W1hi + (size_t)n * HDIM + k) = hh;
  float s2 = w.x*bb.x + w.y*bb.y + w.z*bb.z + w.w*bb.w;
#pragma unroll
  for (int off = 32; off > 0; off >>= 1) {
    s1 += __shfl_down(s1, off, 64);
    s2 += __shfl_down(s2, off, 64);
  }
  __shared__ float t1[4], t2[4];
  const int wv = tid >> 6, ln = tid & 63;
  if (ln == 0) { t1[wv] = s1; t2[wv] = s2; }
  __syncthreads();
  if (tid == 0) {
    v1[n] = t1[0] + t1[1] + t1[2] + t1[3];
    v2[n] = t2[0] + t2[1] + t2[2] + t2[3] + b1[n];
  }
}

// Wxt[j][g*4+c] = W_ih[g*H+j][512+c]  (rank-4 extra weights, fp32)
__global__ __launch_bounds__(256)
void build_wx(const float* __restrict__ Wih, float* __restrict__ Wxt) {
  int rp = blockIdx.x * 256 + threadIdx.x;
  if (rp >= GDIM) return;
  const int jj = rp >> 2, g = rp & 3;
  const int sr = g * HDIM + jj;
  const float4 v = *(const float4*)(Wih + (size_t)sr * 516 + 512);
  *(float4*)(Wxt + (size_t)jj * 16 + g * 4) = v;
}

// Wih_cat [4096][1536] = [lo_s | hi | hi] of W_ih[:, :512], rows interleaved
__global__ __launch_bounds__(256)
void build_wih_cat(const float* __restrict__ Wih, half_t* __restrict__ dst) {
  int idx = blockIdx.x * 256 + threadIdx.x;
  if (idx >= GDIM * 384) return;
  const int rp = idx / 384;
  const int k  = (idx - rp * 384) * 4;
  const int sr = (rp & 3) * HDIM + (rp >> 2);
  const bool lo = (k < 512);
  const int kk = lo ? k : (k < 1024 ? k - 512 : k - 1024);
  const float4 v = *(const float4*)(Wih + (size_t)sr * 516 + kk);
  half_t* d = dst + (size_t)rp * 1536 + k;
  if (lo) { halfx4 o = { lo16(v.x), lo16(v.y), lo16(v.z), lo16(v.w) }; *(halfx4*)d = o; }
  else    { halfx4 o = { hi16(v.x), hi16(v.y), hi16(v.z), hi16(v.w) }; *(halfx4*)d = o; }
}

// bias_i[r'] = b_ih[src] + b_hh[src]
__global__ __launch_bounds__(256)
void build_bias(const float* __restrict__ b_ih, const float* __restrict__ b_hh,
                float* __restrict__ bias_i) {
  int rp = blockIdx.x * 256 + threadIdx.x;
  if (rp >= GDIM) return;
  const int sr = (rp & 3) * HDIM + (rp >> 2);
  bias_i[rp] = b_ih[sr] + b_hh[sr];
}

// Wc_cat [1024][1536] = [lo_s | hi | hi] of a [1024][512] fp32 matrix
__global__ __launch_bounds__(128)
void build_wc_cat(const float* __restrict__ W, half_t* __restrict__ dst) {
  const int n = blockIdx.x;
  const int k = threadIdx.x * 4;
  const float4 w = *(const float4*)(W + (size_t)n * CDIM + k);
  halfx4 hl = { lo16(w.x), lo16(w.y), lo16(w.z), lo16(w.w) };
  halfx4 hh = { hi16(w.x), hi16(w.y), hi16(w.z), hi16(w.w) };
  *(halfx4*)(dst + (size_t)n * 1536 + k)        = hl;
  *(halfx4*)(dst + (size_t)n * 1536 + 512 + k)  = hh;
  *(halfx4*)(dst + (size_t)n * 1536 + 1024 + k) = hh;
}

// delta_init = last_delta - b2, so gates t=0 recovers extra from it exactly
__global__ __launch_bounds__(256)
void init_chunk(const float* __restrict__ ld, const float* __restrict__ b2,
                float* __restrict__ delta_init, int M) {
  int b = blockIdx.x * 256 + threadIdx.x;
  if (b >= M) return;
  delta_init[2*b]   = ld[2*b]   - b2[0];
  delta_init[2*b+1] = ld[2*b+1] - b2[1];
}

extern "C" void kernel_launch(void* const* d_in, const int* in_sizes, int n_in,
                              void* d_out, int out_size, void* d_ws, size_t ws_size,
                              hipStream_t stream) {
  const float* context    = (const float*)d_in[0];
  const float* last_pos   = (const float*)d_in[1];
  const float* last_delta = (const float*)d_in[2];
  const float* Wh   = (const float*)d_in[3];
  const float* bh   = (const float*)d_in[4];
  const float* Wc   = (const float*)d_in[5];
  const float* bc   = (const float*)d_in[6];
  const float* W_ih = (const float*)d_in[7];
  const float* b_ih = (const float*)d_in[8];
  const float* W_hh = (const float*)d_in[9];
  const float* b_hh = (const float*)d_in[10];
  const float* ln_g = (const float*)d_in[11];
  const float* ln_b = (const float*)d_in[12];
  const float* W1   = (const float*)d_in[13];
  const float* b1   = (const float*)d_in[14];
  const float* W2   = (const float*)d_in[15];
  const float* b2   = (const float*)d_in[16];
  float* out = (float*)d_out;

  // ---- workspace plan ----
  const size_t stat_bytes =
      (size_t)GDIM * 1024 * 2 +        // Whh16
      (size_t)GDIM * 2048 +            // Whh8
      (size_t)GDIM * 1536 * 2 +        // Wih_cat
      (size_t)HDIM * 1024 * 2 +        // W1hi
      (size_t)HDIM * 2048 +            // W18
      2 * (size_t)HDIM * 1536 * 2 +    // Wh_cat + Wc_cat
      (size_t)HDIM * 16 * 4 + (size_t)GDIM * 4 + 2 * (size_t)HDIM * 4 + 32768;
  int NC = 0;
  for (int nc : {2, 4, 8, 16}) {
    const size_t M = BATCH / nc;
    const size_t chunk_bytes = 2 * M * HDIM * 2 +       // h hi x2
                               2 * M * 2048 +            // h8 x2
                               2 * M * CDIM * 2 +        // ctx hi/lo
                               M * HDIM * 4 +            // c
                               (size_t)M * GDIM * 4 +    // gctx
                               M * 2 * 4 +               // dinit
                               2 * (size_t)TSTEP * M * 2 * 4 + 32768;
    if (stat_bytes + chunk_bytes <= ws_size) { NC = nc; break; }
  }
  if (NC == 0) return;
  const int M = BATCH / NC;

  char* w = (char*)d_ws;
  auto take = [&](size_t bytes) {
    char* p = w;
    w += (bytes + 255) & ~(size_t)255;
    return p;
  };
  half_t* Whh16   = (half_t*)take((size_t)GDIM * 1024 * 2);
  i8_t*   Whh8    = (i8_t*)take((size_t)GDIM * 2048);
  half_t* Wih_cat = (half_t*)take((size_t)GDIM * 1536 * 2);
  half_t* W1hi    = (half_t*)take((size_t)HDIM * 1024 * 2);
  i8_t*   W18     = (i8_t*)take((size_t)HDIM * 2048);
  half_t* Wh_cat  = (half_t*)take((size_t)HDIM * 1536 * 2);
  half_t* Wc_cat  = (half_t*)take((size_t)HDIM * 1536 * 2);
  float*  Wxt     = (float*)take((size_t)HDIM * 16 * 4);
  float*  bias_i  = (float*)take((size_t)GDIM * 4);
  float*  v1      = (float*)take((size_t)HDIM * 4);
  float*  v2      = (float*)take((size_t)HDIM * 4);
  unsigned* mx    = (unsigned*)take(256);
  int*    Ebuf    = (int*)take(256);
  half_t* h0hi    = (half_t*)take((size_t)M * HDIM * 2);
  half_t* h1hi    = (half_t*)take((size_t)M * HDIM * 2);
  i8_t*   h08     = (i8_t*)take((size_t)M * 2048);
  i8_t*   h18     = (i8_t*)take((size_t)M * 2048);
  half_t* ctx_hi  = (half_t*)take((size_t)M * CDIM * 2);
  half_t* ctx_lo  = (half_t*)take((size_t)M * CDIM * 2);
  float*  c_f     = (float*)take((size_t)M * HDIM * 4);
  float*  gctx    = (float*)take((size_t)M * GDIM * 4);
  float*  dinit   = (float*)take((size_t)M * 2 * 4);
  const size_t sd_bytes = 2 * (size_t)TSTEP * M * 2 * 4;
  float*  statsAll = (float*)take(sd_bytes);            // [60][M][2] stats
  float*  deltaAll = statsAll + (size_t)TSTEP * M * 2;  // [60][M][2] delta

  // static builders (once)
  hipMemsetAsync(mx, 0, 8, stream);
  wmax_reduce<<<256, 256, 0, stream>>>(W_hh, mx, GDIM * HDIM);
  wmax_w1g<<<256, 256, 0, stream>>>(W1, ln_g, mx + 1);
  set_E<<<1, 1, 0, stream>>>(mx, Ebuf);
  build_whh_hyb<<<(GDIM * HDIM + 255) / 256, 256, 0, stream>>>(W_hh, Ebuf, Whh16, Whh8);
  build_w1_hyb<<<HDIM, 256, 0, stream>>>(W1, ln_g, ln_b, b1, Ebuf, W1hi, W18, v1, v2);
  build_wx<<<(GDIM + 255) / 256, 256, 0, stream>>>(W_ih, Wxt);
  build_wih_cat<<<(GDIM * 384 + 255) / 256, 256, 0, stream>>>(W_ih, Wih_cat);
  build_bias<<<(GDIM + 255) / 256, 256, 0, stream>>>(b_ih, b_hh, bias_i);
  build_wc_cat<<<HDIM, 128, 0, stream>>>(Wh, Wh_cat);
  build_wc_cat<<<HDIM, 128, 0, stream>>>(Wc, Wc_cat);

  const dim3 blk(256);
  for (int chunk = 0; chunk < NC; ++chunk) {
    const size_t base = (size_t)chunk * M;
    hipMemsetAsync(statsAll, 0, sd_bytes, stream);
    cvt_split<<<(M * CDIM / 4 + 255) / 256, 256, 0, stream>>>(
        context + base * CDIM, ctx_hi, ctx_lo, M * CDIM / 4);
    gemm3_pre<1, true ><<<dim3(M/128, HDIM/128), blk, 0, stream>>>(
        ctx_hi, ctx_lo, Wh_cat, bh, nullptr, h0hi, h08, HDIM);
    gemm3_pre<1, false><<<dim3(M/128, HDIM/128), blk, 0, stream>>>(
        ctx_hi, ctx_lo, Wc_cat, bc, c_f, nullptr, nullptr, HDIM);
    gemm3_pre<0, false><<<dim3(M/128, GDIM/128), blk, 0, stream>>>(
        ctx_hi, ctx_lo, Wih_cat, bias_i, gctx, nullptr, nullptr, GDIM);
    init_chunk<<<(M + 255) / 256, 256, 0, stream>>>(
        last_delta + base * 2, b2, dinit, M);

    const half_t* hAhi = h0hi;
    const i8_t* hA8 = h08;
    half_t* hBhi = h1hi;
    i8_t* hB8 = h18;
    for (int t = 0; t < TSTEP; ++t) {
      const float* dprev = (t == 0) ? dinit : deltaAll + (size_t)(t - 1) * M * 2;
      gemm_gates_cell<<<dim3(M/128, GDIM/128), blk, 0, stream>>>(
          hAhi, hA8, Whh16, Whh8, Ebuf, gctx, dprev, b2, Wxt, c_f,
          hBhi, hB8, statsAll + (size_t)t * M * 2);
      gemm_mlp64<<<dim3(M/128, HDIM/64), blk, 0, stream>>>(
          hBhi, hB8, W1hi, W18, Ebuf, statsAll + (size_t)t * M * 2, v1, v2, W2,
          deltaAll + (size_t)t * M * 2);
      half_t* th = hBhi; hBhi = (half_t*)hAhi; hAhi = th;
      i8_t* t8 = hB8; hB8 = (i8_t*)hA8; hA8 = t8;
    }
    write_traj<<<(M + 255) / 256, 256, 0, stream>>>(
        last_pos + base * 2, deltaAll, b2, out + base * TSTEP * 2, M);
  }
  (void)in_sizes; (void)n_in; (void)out_size;
}

// Round 14
// 35789.453 us; speedup vs baseline: 1.3617x; 1.0149x over previous
//
#include <hip/hip_runtime.h>
#include <math.h>

constexpr int BATCH = 16384;
constexpr int CDIM  = 512;
constexpr int HDIM  = 1024;
constexpr int GDIM  = 4096;   // 4*H
constexpr int TSTEP = 60;
// split-fp16: x = hi + lo (|lo| <= 2^-12). Hybrid GEMMs (gates & MLP):
//   main:        hi x Whi   fp16 MFMA, f32 acc (products exact in f32)
//   corrections: hi x Wlo + lo x Whi  as ONE int8 GEMM (2x rate), both
//   cross-terms quantized to a shared 2^(25-E) fixed-point scale.
constexpr float LOSC  = 2048.0f;       // 2^11 (fp16 lo limb pre-scale)
constexpr float ILOSC = 1.0f / 2048.0f;

typedef _Float16 half_t;
typedef _Float16 halfx8 __attribute__((ext_vector_type(8)));
typedef _Float16 halfx4 __attribute__((ext_vector_type(4)));
typedef float    f32x4  __attribute__((ext_vector_type(4)));
typedef int      i32x4  __attribute__((ext_vector_type(4)));
typedef signed char i8_t;

__device__ __forceinline__ void async_cp16(const void* g, void* l) {
  __builtin_amdgcn_global_load_lds((__attribute__((address_space(1))) void*)g,
                                   (__attribute__((address_space(3))) void*)l,
                                   16, 0, 0);
}

__device__ __forceinline__ half_t hi16(float x) { return (half_t)x; }
__device__ __forceinline__ half_t lo16(float x) {
  return (half_t)((x - (float)((half_t)x)) * LOSC);
}
__device__ __forceinline__ int clamp8(int v) {
  return v > 127 ? 127 : (v < -127 ? -127 : v);
}
__device__ __forceinline__ float sigf(float x) { return 1.0f / (1.0f + expf(-x)); }
__device__ __forceinline__ float geluf(float v) {
  return 0.5f * v * (1.0f + erff(v * 0.70710678118f));
}

// XCD-aware tile swizzle (r8: neutral but harmless; kept).
__device__ __forceinline__ void swizzle_tiles(int& mt, int& nt) {
  const int gx = gridDim.x, gy = gridDim.y;
  if (gy & 7) { mt = blockIdx.x; nt = blockIdx.y; return; }
  const int lin = blockIdx.y * gx + blockIdx.x;
  const int xcd = lin & 7;
  const int slot = lin >> 3;
  const int npx = gy >> 3;
  nt = xcd * npx + (slot % npx);
  mt = slot / npx;
}

// ---------- one BK=32 fp16 step, 128x128 tile ----------
__device__ __forceinline__ void kstep(f32x4 (&acc)[4][4],
    const half_t* __restrict__ A, size_t lda, int krel,
    const half_t* __restrict__ W, size_t ldw, int kw,
    half_t* sA, half_t* sB, int bm0, int bn0) {
  const int tid  = threadIdx.x;
  const int lane = tid & 63;
  const int wave = tid >> 6;
  const int wm = wave >> 1, wn = wave & 1;
  const int ar = lane >> 2;
  const int ak = (lane & 3) * 8;
  const int quad = lane >> 4;
  const int lcol = lane & 15;
#pragma unroll
  for (int cc = 0; cc < 2; ++cc) {
    const int chunk = wave + cc * 4;
    async_cp16(A + (size_t)(bm0 + chunk * 16 + ar) * lda + (krel + ak), sA + chunk * 512);
    async_cp16(W + (size_t)(bn0 + chunk * 16 + ar) * ldw + (kw + ak), sB + chunk * 512);
  }
  asm volatile("s_waitcnt vmcnt(0)" ::: "memory");
  __syncthreads();
  halfx8 af[4], bfr[4];
#pragma unroll
  for (int mi = 0; mi < 4; ++mi)
    af[mi] = *(const halfx8*)&sA[(wm * 64 + mi * 16 + lcol) * 32 + quad * 8];
#pragma unroll
  for (int ni = 0; ni < 4; ++ni)
    bfr[ni] = *(const halfx8*)&sB[(wn * 64 + ni * 16 + lcol) * 32 + quad * 8];
#pragma unroll
  for (int mi = 0; mi < 4; ++mi)
#pragma unroll
    for (int ni = 0; ni < 4; ++ni)
      acc[mi][ni] = __builtin_amdgcn_mfma_f32_16x16x32_f16(af[mi], bfr[ni], acc[mi][ni], 0, 0, 0);
  __syncthreads();
}

__device__ __forceinline__ void scale_acc4(f32x4 (&acc)[4][4], float s) {
#pragma unroll
  for (int i = 0; i < 4; ++i)
#pragma unroll
    for (int j = 0; j < 4; ++j) acc[i][j] *= s;
}

// ---------- preamble split GEMM (K=1536: [Wlo_s x Ahi | Whi x Alo_s | Whi x Ahi])
template <int ACT, bool SPLITOUT>   // ACT: 0=none 1=tanh
__global__ __launch_bounds__(256, 3)
void gemm3_pre(const half_t* __restrict__ Ahi, const half_t* __restrict__ Alo,
               const half_t* __restrict__ Wcat, const float* __restrict__ bias,
               float* __restrict__ Cf, half_t* __restrict__ Chi,
               i8_t* __restrict__ C8, int ldc) {
  __shared__ __align__(16) half_t sA[128 * 32];
  __shared__ __align__(16) half_t sB[128 * 32];
  const int tid = threadIdx.x;
  int mt, nt;
  swizzle_tiles(mt, nt);
  const int bm0 = mt * 128, bn0 = nt * 128;
  f32x4 acc[4][4];
#pragma unroll
  for (int i = 0; i < 4; ++i)
#pragma unroll
    for (int j = 0; j < 4; ++j) acc[i][j] = (f32x4){0.f, 0.f, 0.f, 0.f};
#pragma unroll 1
  for (int k0 = 0; k0 < 512; k0 += 32)
    kstep(acc, Ahi, CDIM, k0, Wcat, 1536, k0, sA, sB, bm0, bn0);
#pragma unroll 1
  for (int k0 = 512; k0 < 1024; k0 += 32)
    kstep(acc, Alo, CDIM, k0 - 512, Wcat, 1536, k0, sA, sB, bm0, bn0);
  scale_acc4(acc, ILOSC);
#pragma unroll 1
  for (int k0 = 1024; k0 < 1536; k0 += 32)
    kstep(acc, Ahi, CDIM, k0 - 1024, Wcat, 1536, k0, sA, sB, bm0, bn0);

  const int lane = tid & 63, wave = tid >> 6;
  const int wm = wave >> 1, wn = wave & 1, quad = lane >> 4, lcol = lane & 15;
#pragma unroll
  for (int ni = 0; ni < 4; ++ni) {
    const int col = bn0 + wn * 64 + ni * 16 + lcol;
    const float bv = bias[col];
#pragma unroll
    for (int mi = 0; mi < 4; ++mi) {
      const int row0 = bm0 + wm * 64 + mi * 16 + quad * 4;
#pragma unroll
      for (int r = 0; r < 4; ++r) {
        float v = acc[mi][ni][r] + bv;
        if (ACT == 1) v = tanhf(v);
        if (SPLITOUT) {
          const half_t hh = hi16(v);
          const float hiF = (float)hh;
          Chi[(size_t)(row0 + r) * ldc + col] = hh;
          const int hq = clamp8((int)rintf(hiF * 128.0f));
          const int lq = clamp8((int)rintf((v - hiF) * 524288.0f));  // 2^19
          C8[(size_t)(row0 + r) * 2048 + col]        = (i8_t)hq;
          C8[(size_t)(row0 + r) * 2048 + 1024 + col] = (i8_t)lq;
        } else {
          Cf[(size_t)(row0 + r) * ldc + col] = v;
        }
      }
    }
  }
}

// ---------- fused gates GEMM (int8 corrections + fp16 main) + LSTM cell ----------
__global__ __launch_bounds__(256, 3)
void gemm_gates_cell(const half_t* __restrict__ hAhi, const i8_t* __restrict__ hA8,
                     const half_t* __restrict__ Whh16, const i8_t* __restrict__ Whh8,
                     const int* __restrict__ Ebuf,
                     const float* __restrict__ gctx,
                     const float* __restrict__ dprev, const float* __restrict__ b2,
                     const float* __restrict__ Wxt, float* __restrict__ c,
                     half_t* __restrict__ hBhi, i8_t* __restrict__ hB8,
                     float* __restrict__ statsT) {
  __shared__ __align__(16) unsigned char sAraw[8192];
  __shared__ __align__(16) unsigned char sBraw[8192];
  __shared__ __align__(16) float sE[4][16 * 68];
  const int tid = threadIdx.x;
  const int lane = tid & 63;
  const int wave = tid >> 6;
  const int wm = wave >> 1, wn = wave & 1;
  const int quad = lane >> 4;
  const int lcol = lane & 15;
  int mt, nt;
  swizzle_tiles(mt, nt);
  const int bm0 = mt * 128, bn0 = nt * 128;

  // ---- phase 1: int8 corrections, K=2048 bytes, BK=64 ----
  i32x4 acc8[4][4];
#pragma unroll
  for (int i = 0; i < 4; ++i)
#pragma unroll
    for (int j = 0; j < 4; ++j) acc8[i][j] = (i32x4){0, 0, 0, 0};
  {
    const int ar8 = lane >> 2;
    const int ab8 = (lane & 3) * 16;
#pragma unroll 1
    for (int k0 = 0; k0 < 2048; k0 += 64) {
#pragma unroll
      for (int cc = 0; cc < 2; ++cc) {
        const int chunk = wave + cc * 4;
        async_cp16(hA8 + (size_t)(bm0 + chunk * 16 + ar8) * 2048 + (k0 + ab8),
                   sAraw + chunk * 1024);
        async_cp16(Whh8 + (size_t)(bn0 + chunk * 16 + ar8) * 2048 + (k0 + ab8),
                   sBraw + chunk * 1024);
      }
      asm volatile("s_waitcnt vmcnt(0)" ::: "memory");
      __syncthreads();
      i32x4 ai[4], bi[4];
#pragma unroll
      for (int mi = 0; mi < 4; ++mi)
        ai[mi] = *(const i32x4*)&sAraw[(wm * 64 + mi * 16 + lcol) * 64 + quad * 16];
#pragma unroll
      for (int ni = 0; ni < 4; ++ni)
        bi[ni] = *(const i32x4*)&sBraw[(wn * 64 + ni * 16 + lcol) * 64 + quad * 16];
#pragma unroll
      for (int mi = 0; mi < 4; ++mi)
#pragma unroll
        for (int ni = 0; ni < 4; ++ni)
          acc8[mi][ni] = __builtin_amdgcn_mfma_i32_16x16x64_i8(ai[mi], bi[ni], acc8[mi][ni], 0, 0, 0);
      __syncthreads();
    }
  }
  const int E = Ebuf[0];
  f32x4 acc[4][4];
#pragma unroll
  for (int i = 0; i < 4; ++i)
#pragma unroll
    for (int j = 0; j < 4; ++j)
#pragma unroll
      for (int r = 0; r < 4; ++r)
        acc[i][j][r] = ldexpf((float)acc8[i][j][r], E - 25);

  // ---- phase 2: fp16 main (hi x Whi), K=1024, BK=32 ----
#pragma unroll 1
  for (int k0 = 0; k0 < 1024; k0 += 32)
    kstep(acc, hAhi, HDIM, k0, Whh16, 1024, k0,
          (half_t*)sAraw, (half_t*)sBraw, bm0, bn0);

  // ---- epilogue ----
  float* myE = sE[wave];
  const int u = lane & 15;
  const int q = lane >> 4;
  const int j = ((bn0 + wn * 64) >> 2) + u;
  const float b20 = b2[0], b21 = b2[1];
  const float4 wx0 = *(const float4*)(Wxt + (size_t)j * 16 + 0);
  const float4 wx1 = *(const float4*)(Wxt + (size_t)j * 16 + 4);
  const float4 wx2 = *(const float4*)(Wxt + (size_t)j * 16 + 8);
  const float4 wx3 = *(const float4*)(Wxt + (size_t)j * 16 + 12);

#pragma unroll
  for (int mi = 0; mi < 4; ++mi) {
#pragma unroll
    for (int ni = 0; ni < 4; ++ni)
#pragma unroll
      for (int r = 0; r < 4; ++r)
        myE[(quad * 4 + r) * 68 + ni * 16 + lcol] = acc[mi][ni][r];
    // same-wave DS ops are in-order: reads below see the writes above
#pragma unroll
    for (int k = 0; k < 4; ++k) {
      const int rr = q + 4 * k;
      const int row = bm0 + wm * 64 + mi * 16 + rr;
      const f32x4 gv = *(const f32x4*)&myE[rr * 68 + u * 4];  // {i,f,g,o} h-part
      const float4 gc = *(const float4*)(gctx + (size_t)row * GDIM + 4 * j);
      const float dx = dprev[2 * row] + b20;
      const float dy = dprev[2 * row + 1] + b21;
      const float nrm = fmaxf(sqrtf(dx * dx + dy * dy), 1e-6f);
      const float ex = dx, ey = dy, ehx = dx / nrm, ehy = dy / nrm;
      const float pi = gv[0] + gc.x + ex*wx0.x + ey*wx0.y + ehx*wx0.z + ehy*wx0.w;
      const float pf = gv[1] + gc.y + ex*wx1.x + ey*wx1.y + ehx*wx1.z + ehy*wx1.w;
      const float pg = gv[2] + gc.z + ex*wx2.x + ey*wx2.y + ehx*wx2.z + ehy*wx2.w;
      const float po = gv[3] + gc.w + ex*wx3.x + ey*wx3.y + ehx*wx3.z + ehy*wx3.w;
      const size_t cidx = (size_t)row * HDIM + j;
      const float cn = sigf(pf) * c[cidx] + sigf(pi) * tanhf(pg);
      c[cidx] = cn;
      const float vh = sigf(po) * tanhf(cn);
      const half_t hh = hi16(vh);
      const float hiF = (float)hh;
      hBhi[cidx] = hh;
      const int hq = clamp8((int)rintf(hiF * 128.0f));
      const int lq = clamp8((int)rintf((vh - hiF) * 524288.0f));  // 2^19
      hB8[(size_t)row * 2048 + j]        = (i8_t)hq;
      hB8[(size_t)row * 2048 + 1024 + j] = (i8_t)lq;
      float ps = vh, pq = vh * vh;
#pragma unroll
      for (int m = 1; m < 16; m <<= 1) {
        ps += __shfl_xor(ps, m, 64);
        pq += __shfl_xor(pq, m, 64);
      }
      if (u == 0) {
        atomicAdd(&statsT[2 * row], ps);
        atomicAdd(&statsT[2 * row + 1], pq);
      }
    }
  }
}

// ---------- MLP GEMM, 128x64 tile, int8 corrections + fp16 main ----------
__global__ __launch_bounds__(256, 3)
void gemm_mlp64(const half_t* __restrict__ hBhi, const i8_t* __restrict__ hB8,
                const half_t* __restrict__ W1hi, const i8_t* __restrict__ W18,
                const int* __restrict__ Ebuf, const float* __restrict__ statsT,
                const float* __restrict__ v1, const float* __restrict__ v2,
                const float* __restrict__ W2, float* __restrict__ deltaT) {
  __shared__ __align__(16) unsigned char sAraw[8192];
  __shared__ __align__(16) unsigned char sBraw[4096];
  const int tid = threadIdx.x;
  const int lane = tid & 63;
  const int wave = tid >> 6;
  const int quad = lane >> 4;
  const int lcol = lane & 15;
  int mt, nt;
  swizzle_tiles(mt, nt);
  const int bm0 = mt * 128, bn0 = nt * 64;

  // ---- phase 1: int8 corrections ----
  i32x4 acc8[2][4];
#pragma unroll
  for (int i = 0; i < 2; ++i)
#pragma unroll
    for (int jj = 0; jj < 4; ++jj) acc8[i][jj] = (i32x4){0, 0, 0, 0};
  {
    const int ar8 = lane >> 2;
    const int ab8 = (lane & 3) * 16;
#pragma unroll 1
    for (int k0 = 0; k0 < 2048; k0 += 64) {
#pragma unroll
      for (int cc = 0; cc < 2; ++cc) {
        const int chunk = wave + cc * 4;
        async_cp16(hB8 + (size_t)(bm0 + chunk * 16 + ar8) * 2048 + (k0 + ab8),
                   sAraw + chunk * 1024);
      }
      async_cp16(W18 + (size_t)(bn0 + wave * 16 + ar8) * 2048 + (k0 + ab8),
                 sBraw + wave * 1024);
      asm volatile("s_waitcnt vmcnt(0)" ::: "memory");
      __syncthreads();
      i32x4 ai[2], bi[4];
#pragma unroll
      for (int mi = 0; mi < 2; ++mi)
        ai[mi] = *(const i32x4*)&sAraw[(wave * 32 + mi * 16 + lcol) * 64 + quad * 16];
#pragma unroll
      for (int ni = 0; ni < 4; ++ni)
        bi[ni] = *(const i32x4*)&sBraw[(ni * 16 + lcol) * 64 + quad * 16];
#pragma unroll
      for (int mi = 0; mi < 2; ++mi)
#pragma unroll
        for (int ni = 0; ni < 4; ++ni)
          acc8[mi][ni] = __builtin_amdgcn_mfma_i32_16x16x64_i8(ai[mi], bi[ni], acc8[mi][ni], 0, 0, 0);
      __syncthreads();
    }
  }
  const int E1 = Ebuf[1];
  f32x4 accM[2][4];
#pragma unroll
  for (int i = 0; i < 2; ++i)
#pragma unroll
    for (int jj = 0; jj < 4; ++jj)
#pragma unroll
      for (int r = 0; r < 4; ++r)
        accM[i][jj][r] = ldexpf((float)acc8[i][jj][r], E1 - 25);

  // ---- phase 2: fp16 main (h_hi x W1hi), K=1024, BK=32 ----
  {
    half_t* sA = (half_t*)sAraw;
    half_t* sB = (half_t*)sBraw;
    const int ar = lane >> 2;
    const int ak = (lane & 3) * 8;
#pragma unroll 1
    for (int k0 = 0; k0 < 1024; k0 += 32) {
#pragma unroll
      for (int cc = 0; cc < 2; ++cc) {
        const int chunk = wave + cc * 4;
        async_cp16(hBhi + (size_t)(bm0 + chunk * 16 + ar) * HDIM + (k0 + ak), sA + chunk * 512);
      }
      async_cp16(W1hi + (size_t)(bn0 + wave * 16 + ar) * HDIM + (k0 + ak), sB + wave * 512);
      asm volatile("s_waitcnt vmcnt(0)" ::: "memory");
      __syncthreads();
      halfx8 af[2], bfr[4];
#pragma unroll
      for (int mi = 0; mi < 2; ++mi)
        af[mi] = *(const halfx8*)&sA[(wave * 32 + mi * 16 + lcol) * 32 + quad * 8];
#pragma unroll
      for (int ni = 0; ni < 4; ++ni)
        bfr[ni] = *(const halfx8*)&sB[(ni * 16 + lcol) * 32 + quad * 8];
#pragma unroll
      for (int mi = 0; mi < 2; ++mi)
#pragma unroll
        for (int ni = 0; ni < 4; ++ni)
          accM[mi][ni] = __builtin_amdgcn_mfma_f32_16x16x32_f16(af[mi], bfr[ni], accM[mi][ni], 0, 0, 0);
      __syncthreads();
    }
  }

  float w2a[4], w2b[4], v1c[4], v2c[4];
#pragma unroll
  for (int ni = 0; ni < 4; ++ni) {
    const int col = bn0 + ni * 16 + lcol;
    w2a[ni] = W2[col]; w2b[ni] = W2[HDIM + col];
    v1c[ni] = v1[col]; v2c[ni] = v2[col];
  }
#pragma unroll
  for (int mi = 0; mi < 2; ++mi) {
#pragma unroll
    for (int r = 0; r < 4; ++r) {
      const int row = bm0 + wave * 32 + mi * 16 + quad * 4 + r;
      const float S = statsT[2 * row], Q = statsT[2 * row + 1];
      const float mu = S * (1.0f / HDIM);
      const float rs = rsqrtf(Q * (1.0f / HDIM) - mu * mu + 1e-5f);
      float d0 = 0.f, d1 = 0.f;
#pragma unroll
      for (int ni = 0; ni < 4; ++ni) {
        const float g = geluf(rs * (accM[mi][ni][r] - mu * v1c[ni]) + v2c[ni]);
        d0 += g * w2a[ni];
        d1 += g * w2b[ni];
      }
#pragma unroll
      for (int m = 1; m < 16; m <<= 1) {
        d0 += __shfl_xor(d0, m, 64);
        d1 += __shfl_xor(d1, m, 64);
      }
      if (lcol == 0) {
        atomicAdd(&deltaT[2 * row], d0);
        atomicAdd(&deltaT[2 * row + 1], d1);
      }
    }
  }
}

// ---------- trajectory writeback: pos cumsum + out (once per chunk) ----------
__global__ __launch_bounds__(256)
void write_traj(const float* __restrict__ lp, const float* __restrict__ deltaT,
                const float* __restrict__ b2, float* __restrict__ out, int M) {
  const int b = blockIdx.x * 256 + threadIdx.x;
  if (b >= M) return;
  float px = lp[2 * b], py = lp[2 * b + 1];
  const float b20 = b2[0], b21 = b2[1];
  for (int t = 0; t < TSTEP; ++t) {
    px += deltaT[(size_t)t * M * 2 + 2 * b] + b20;
    py += deltaT[(size_t)t * M * 2 + 2 * b + 1] + b21;
    out[((size_t)b * TSTEP + t) * 2 + 0] = px;
    out[((size_t)b * TSTEP + t) * 2 + 1] = py;
  }
}

// ---------- builders ----------
__global__ __launch_bounds__(256)
void cvt_split(const float* __restrict__ s, half_t* __restrict__ dhi,
               half_t* __restrict__ dlo, int n4) {
  int i = blockIdx.x * 256 + threadIdx.x;
  if (i >= n4) return;
  const float4 v = ((const float4*)s)[i];
  halfx4 h = { hi16(v.x), hi16(v.y), hi16(v.z), hi16(v.w) };
  halfx4 l = { lo16(v.x), lo16(v.y), lo16(v.z), lo16(v.w) };
  *(halfx4*)(dhi + (size_t)i * 4) = h;
  *(halfx4*)(dlo + (size_t)i * 4) = l;
}

// global max|W_hh| and max|W1*g| -> uint bits (monotonic for non-neg floats)
__global__ __launch_bounds__(256)
void wmax_reduce(const float* __restrict__ W, unsigned* __restrict__ mx, int n) {
  float m = 0.f;
  for (int i = blockIdx.x * 256 + threadIdx.x; i < n; i += gridDim.x * 256)
    m = fmaxf(m, fabsf(W[i]));
#pragma unroll
  for (int off = 32; off > 0; off >>= 1)
    m = fmaxf(m, __shfl_down(m, off, 64));
  if ((threadIdx.x & 63) == 0) atomicMax(mx, __float_as_uint(m));
}

__global__ __launch_bounds__(256)
void wmax_w1g(const float* __restrict__ W1, const float* __restrict__ g,
              unsigned* __restrict__ mx) {
  float m = 0.f;
  for (int i = blockIdx.x * 256 + threadIdx.x; i < HDIM * HDIM; i += gridDim.x * 256)
    m = fmaxf(m, fabsf(W1[i] * g[i & 1023]));
#pragma unroll
  for (int off = 32; off > 0; off >>= 1)
    m = fmaxf(m, __shfl_down(m, off, 64));
  if ((threadIdx.x & 63) == 0) atomicMax(mx, __float_as_uint(m));
}

__global__ void set_E(const unsigned* __restrict__ mx, int* __restrict__ Ebuf) {
  int e;
  frexpf(__uint_as_float(mx[0]), &e);
  Ebuf[0] = e - 1;
  frexpf(__uint_as_float(mx[1]), &e);
  Ebuf[1] = e - 1;
}

// Whh16 [4096][1024] fp16 (hi of W_hh, rows interleaved r'=4u+g)
// Whh8  [4096][2048] int8: [0,1024)=wloq (~Wlo*2^(18-E)), [1024,2048)=whiq (~Whi*2^(6-E))
__global__ __launch_bounds__(256)
void build_whh_hyb(const float* __restrict__ Whh, const int* __restrict__ Ebuf,
                   half_t* __restrict__ W16, i8_t* __restrict__ W8) {
  int idx = blockIdx.x * 256 + threadIdx.x;
  if (idx >= GDIM * HDIM) return;
  const int rp = idx >> 10;
  const int k  = idx & 1023;
  const int sr = (rp & 3) * HDIM + (rp >> 2);
  const float w = Whh[(size_t)sr * HDIM + k];
  const half_t whi = (half_t)w;
  const float hiF = (float)whi;
  const float wlo = w - hiF;
  const int E = Ebuf[0];
  W16[(size_t)rp * 1024 + k] = whi;
  W8[(size_t)rp * 2048 + k]        = (i8_t)clamp8((int)rintf(ldexpf(wlo, 18 - E)));
  W8[(size_t)rp * 2048 + 1024 + k] = (i8_t)clamp8((int)rintf(ldexpf(hiF, 6 - E)));
}

// W1hi [1024][1024] fp16 hi of W1*ln_g; W18 [1024][2048] = [w1loq | w1hiq];
// v1[n]=sum(W1g row); v2[n]=W1[n]·beta + b1[n]
__global__ __launch_bounds__(256)
void build_w1_hyb(const float* __restrict__ W1, const float* __restrict__ g,
                  const float* __restrict__ beta, const float* __restrict__ b1,
                  const int* __restrict__ Ebuf, half_t* __restrict__ W1hi,
                  i8_t* __restrict__ W18, float* __restrict__ v1,
                  float* __restrict__ v2) {
  const int n = blockIdx.x;
  const int tid = threadIdx.x;
  const int k = tid * 4;
  const int E1 = Ebuf[1];
  const float4 w  = *(const float4*)(W1 + (size_t)n * HDIM + k);
  const float4 gg = *(const float4*)(g + k);
  const float4 bb = *(const float4*)(beta + k);
  float wg[4] = { w.x*gg.x, w.y*gg.y, w.z*gg.z, w.w*gg.w };
  halfx4 hh;
  float s1 = 0.f;
#pragma unroll
  for (int u = 0; u < 4; ++u) {
    const half_t h = (half_t)wg[u];
    hh[u] = h;
    const float hiF = (float)h;
    const float lo = wg[u] - hiF;
    W18[(size_t)n * 2048 + k + u]        = (i8_t)clamp8((int)rintf(ldexpf(lo, 18 - E1)));
    W18[(size_t)n * 2048 + 1024 + k + u] = (i8_t)clamp8((int)rintf(ldexpf(hiF, 6 - E1)));
    s1 += wg[u];
  }
  *(halfx4*)(W1hi + (size_t)n * HDIM + k) = hh;
  float s2 = w.x*bb.x + w.y*bb.y + w.z*bb.z + w.w*bb.w;
#pragma unroll
  for (int off = 32; off > 0; off >>= 1) {
    s1 += __shfl_down(s1, off, 64);
    s2 += __shfl_down(s2, off, 64);
  }
  __shared__ float t1[4], t2[4];
  const int wv = tid >> 6, ln = tid & 63;
  if (ln == 0) { t1[wv] = s1; t2[wv] = s2; }
  __syncthreads();
  if (tid == 0) {
    v1[n] = t1[0] + t1[1] + t1[2] + t1[3];
    v2[n] = t2[0] + t2[1] + t2[2] + t2[3] + b1[n];
  }
}

// Wxt[j][g*4+c] = W_ih[g*H+j][512+c]  (rank-4 extra weights, fp32)
__global__ __launch_bounds__(256)
void build_wx(const float* __restrict__ Wih, float* __restrict__ Wxt) {
  int rp = blockIdx.x * 256 + threadIdx.x;
  if (rp >= GDIM) return;
  const int jj = rp >> 2, g = rp & 3;
  const int sr = g * HDIM + jj;
  const float4 v = *(const float4*)(Wih + (size_t)sr * 516 + 512);
  *(float4*)(Wxt + (size_t)jj * 16 + g * 4) = v;
}

// Wih_cat [4096][1536] = [lo_s | hi | hi] of W_ih[:, :512], rows interleaved
__global__ __launch_bounds__(256)
void build_wih_cat(const float* __restrict__ Wih, half_t* __restrict__ dst) {
  int idx = blockIdx.x * 256 + threadIdx.x;
  if (idx >= GDIM * 384) return;
  const int rp = idx / 384;
  const int k  = (idx - rp * 384) * 4;
  const int sr = (rp & 3) * HDIM + (rp >> 2);
  const bool lo = (k < 512);
  const int kk = lo ? k : (k < 1024 ? k - 512 : k - 1024);
  const float4 v = *(const float4*)(Wih + (size_t)sr * 516 + kk);
  half_t* d = dst + (size_t)rp * 1536 + k;
  if (lo) { halfx4 o = { lo16(v.x), lo16(v.y), lo16(v.z), lo16(v.w) }; *(halfx4*)d = o; }
  else    { halfx4 o = { hi16(v.x), hi16(v.y), hi16(v.z), hi16(v.w) }; *(halfx4*)d = o; }
}

// bias_i[r'] = b_ih[src] + b_hh[src]
__global__ __launch_bounds__(256)
void build_bias(const float* __restrict__ b_ih, const float* __restrict__ b_hh,
                float* __restrict__ bias_i) {
  int rp = blockIdx.x * 256 + threadIdx.x;
  if (rp >= GDIM) return;
  const int sr = (rp & 3) * HDIM + (rp >> 2);
  bias_i[rp] = b_ih[sr] + b_hh[sr];
}

// Wc_cat [1024][1536] = [lo_s | hi | hi] of a [1024][512] fp32 matrix
__global__ __launch_bounds__(128)
void build_wc_cat(const float* __restrict__ W, half_t* __restrict__ dst) {
  const int n = blockIdx.x;
  const int k = threadIdx.x * 4;
  const float4 w = *(const float4*)(W + (size_t)n * CDIM + k);
  halfx4 hl = { lo16(w.x), lo16(w.y), lo16(w.z), lo16(w.w) };
  halfx4 hh = { hi16(w.x), hi16(w.y), hi16(w.z), hi16(w.w) };
  *(halfx4*)(dst + (size_t)n * 1536 + k)        = hl;
  *(halfx4*)(dst + (size_t)n * 1536 + 512 + k)  = hh;
  *(halfx4*)(dst + (size_t)n * 1536 + 1024 + k) = hh;
}

// delta_init = last_delta - b2, so gates t=0 recovers extra from it exactly
__global__ __launch_bounds__(256)
void init_chunk(const float* __restrict__ ld, const float* __restrict__ b2,
                float* __restrict__ delta_init, int M) {
  int b = blockIdx.x * 256 + threadIdx.x;
  if (b >= M) return;
  delta_init[2*b]   = ld[2*b]   - b2[0];
  delta_init[2*b+1] = ld[2*b+1] - b2[1];
}

extern "C" void kernel_launch(void* const* d_in, const int* in_sizes, int n_in,
                              void* d_out, int out_size, void* d_ws, size_t ws_size,
                              hipStream_t stream) {
  const float* context    = (const float*)d_in[0];
  const float* last_pos   = (const float*)d_in[1];
  const float* last_delta = (const float*)d_in[2];
  const float* Wh   = (const float*)d_in[3];
  const float* bh   = (const float*)d_in[4];
  const float* Wc   = (const float*)d_in[5];
  const float* bc   = (const float*)d_in[6];
  const float* W_ih = (const float*)d_in[7];
  const float* b_ih = (const float*)d_in[8];
  const float* W_hh = (const float*)d_in[9];
  const float* b_hh = (const float*)d_in[10];
  const float* ln_g = (const float*)d_in[11];
  const float* ln_b = (const float*)d_in[12];
  const float* W1   = (const float*)d_in[13];
  const float* b1   = (const float*)d_in[14];
  const float* W2   = (const float*)d_in[15];
  const float* b2   = (const float*)d_in[16];
  float* out = (float*)d_out;

  // ---- workspace plan: shared weights + NSTR parallel chain buffers ----
  const size_t stat_bytes =
      (size_t)GDIM * 1024 * 2 + (size_t)GDIM * 2048 + (size_t)GDIM * 1536 * 2 +
      (size_t)HDIM * 1024 * 2 + (size_t)HDIM * 2048 +
      2 * (size_t)HDIM * 1536 * 2 +
      (size_t)HDIM * 16 * 4 + (size_t)GDIM * 4 + 2 * (size_t)HDIM * 4 + 32768;
  auto chain_bytes = [](size_t M) {
    return 2 * M * HDIM * 2 +          // h hi ping/pong
           2 * M * 2048 +              // h8 ping/pong
           2 * M * CDIM * 2 +          // ctx hi/lo
           M * HDIM * 4 +              // c
           M * (size_t)GDIM * 4 +      // gctx
           M * 2 * 4 +                 // dinit
           2 * (size_t)TSTEP * M * 2 * 4 + 65536;  // stats+delta slices
  };
  int NSTR = 0, M = 0;
  const int cand[5][2] = { {4, 2048}, {2, 2048}, {2, 1024}, {1, 2048}, {1, 1024} };
  for (int ci = 0; ci < 5; ++ci) {
    if (stat_bytes + (size_t)cand[ci][0] * chain_bytes(cand[ci][1]) <= ws_size) {
      NSTR = cand[ci][0]; M = cand[ci][1]; break;
    }
  }
  if (NSTR == 0) return;
  const int NCHUNK = BATCH / M;

  char* w = (char*)d_ws;
  auto take = [&](size_t bytes) {
    char* p = w;
    w += (bytes + 255) & ~(size_t)255;
    return p;
  };
  half_t* Whh16   = (half_t*)take((size_t)GDIM * 1024 * 2);
  i8_t*   Whh8    = (i8_t*)take((size_t)GDIM * 2048);
  half_t* Wih_cat = (half_t*)take((size_t)GDIM * 1536 * 2);
  half_t* W1hi    = (half_t*)take((size_t)HDIM * 1024 * 2);
  i8_t*   W18     = (i8_t*)take((size_t)HDIM * 2048);
  half_t* Wh_cat  = (half_t*)take((size_t)HDIM * 1536 * 2);
  half_t* Wc_cat  = (half_t*)take((size_t)HDIM * 1536 * 2);
  float*  Wxt     = (float*)take((size_t)HDIM * 16 * 4);
  float*  bias_i  = (float*)take((size_t)GDIM * 4);
  float*  v1      = (float*)take((size_t)HDIM * 4);
  float*  v2      = (float*)take((size_t)HDIM * 4);
  unsigned* mx    = (unsigned*)take(256);
  int*    Ebuf    = (int*)take(256);

  struct ChainBuf {
    half_t *h0hi, *h1hi;
    i8_t *h08, *h18;
    half_t *ctx_hi, *ctx_lo;
    float *c_f, *gctx, *dinit, *statsAll, *deltaAll;
    size_t sd_bytes;
  };
  ChainBuf cb[4];
  for (int s = 0; s < NSTR; ++s) {
    cb[s].h0hi   = (half_t*)take((size_t)M * HDIM * 2);
    cb[s].h1hi   = (half_t*)take((size_t)M * HDIM * 2);
    cb[s].h08    = (i8_t*)take((size_t)M * 2048);
    cb[s].h18    = (i8_t*)take((size_t)M * 2048);
    cb[s].ctx_hi = (half_t*)take((size_t)M * CDIM * 2);
    cb[s].ctx_lo = (half_t*)take((size_t)M * CDIM * 2);
    cb[s].c_f    = (float*)take((size_t)M * HDIM * 4);
    cb[s].gctx   = (float*)take((size_t)M * GDIM * 4);
    cb[s].dinit  = (float*)take((size_t)M * 2 * 4);
    cb[s].sd_bytes = 2 * (size_t)TSTEP * M * 2 * 4;
    cb[s].statsAll = (float*)take(cb[s].sd_bytes);
    cb[s].deltaAll = cb[s].statsAll + (size_t)TSTEP * M * 2;
  }

  // ---- shared builders (on origin stream, before fork) ----
  hipMemsetAsync(mx, 0, 8, stream);
  wmax_reduce<<<256, 256, 0, stream>>>(W_hh, mx, GDIM * HDIM);
  wmax_w1g<<<256, 256, 0, stream>>>(W1, ln_g, mx + 1);
  set_E<<<1, 1, 0, stream>>>(mx, Ebuf);
  build_whh_hyb<<<(GDIM * HDIM + 255) / 256, 256, 0, stream>>>(W_hh, Ebuf, Whh16, Whh8);
  build_w1_hyb<<<HDIM, 256, 0, stream>>>(W1, ln_g, ln_b, b1, Ebuf, W1hi, W18, v1, v2);
  build_wx<<<(GDIM + 255) / 256, 256, 0, stream>>>(W_ih, Wxt);
  build_wih_cat<<<(GDIM * 384 + 255) / 256, 256, 0, stream>>>(W_ih, Wih_cat);
  build_bias<<<(GDIM + 255) / 256, 256, 0, stream>>>(b_ih, b_hh, bias_i);
  build_wc_cat<<<HDIM, 128, 0, stream>>>(Wh, Wh_cat);
  build_wc_cat<<<HDIM, 128, 0, stream>>>(Wc, Wc_cat);

  // ---- fork secondary streams (multi-stream graph-capture DAG) ----
  hipStream_t str[4];
  str[0] = stream;
  hipEvent_t eFork = nullptr, eJoin[4] = {nullptr, nullptr, nullptr, nullptr};
  if (NSTR > 1) {
    hipEventCreateWithFlags(&eFork, hipEventDisableTiming);
    hipEventRecord(eFork, stream);
    for (int s = 1; s < NSTR; ++s) {
      hipStreamCreateWithFlags(&str[s], hipStreamNonBlocking);
      hipStreamWaitEvent(str[s], eFork, 0);
      hipEventCreateWithFlags(&eJoin[s], hipEventDisableTiming);
    }
  }

  const dim3 blk(256);
  auto run_chunk = [&](hipStream_t st, ChainBuf& B, size_t base) {
    hipMemsetAsync(B.statsAll, 0, B.sd_bytes, st);
    cvt_split<<<(M * CDIM / 4 + 255) / 256, 256, 0, st>>>(
        context + base * CDIM, B.ctx_hi, B.ctx_lo, M * CDIM / 4);
    gemm3_pre<1, true ><<<dim3(M/128, HDIM/128), blk, 0, st>>>(
        B.ctx_hi, B.ctx_lo, Wh_cat, bh, nullptr, B.h0hi, B.h08, HDIM);
    gemm3_pre<1, false><<<dim3(M/128, HDIM/128), blk, 0, st>>>(
        B.ctx_hi, B.ctx_lo, Wc_cat, bc, B.c_f, nullptr, nullptr, HDIM);
    gemm3_pre<0, false><<<dim3(M/128, GDIM/128), blk, 0, st>>>(
        B.ctx_hi, B.ctx_lo, Wih_cat, bias_i, B.gctx, nullptr, nullptr, GDIM);
    init_chunk<<<(M + 255) / 256, 256, 0, st>>>(
        last_delta + base * 2, b2, B.dinit, M);

    const half_t* hAhi = B.h0hi;
    const i8_t* hA8 = B.h08;
    half_t* hBhi = B.h1hi;
    i8_t* hB8 = B.h18;
    for (int t = 0; t < TSTEP; ++t) {
      const float* dprev = (t == 0) ? B.dinit : B.deltaAll + (size_t)(t - 1) * M * 2;
      gemm_gates_cell<<<dim3(M/128, GDIM/128), blk, 0, st>>>(
          hAhi, hA8, Whh16, Whh8, Ebuf, B.gctx, dprev, b2, Wxt, B.c_f,
          hBhi, hB8, B.statsAll + (size_t)t * M * 2);
      gemm_mlp64<<<dim3(M/128, HDIM/64), blk, 0, st>>>(
          hBhi, hB8, W1hi, W18, Ebuf, B.statsAll + (size_t)t * M * 2, v1, v2, W2,
          B.deltaAll + (size_t)t * M * 2);
      half_t* th = hBhi; hBhi = (half_t*)hAhi; hAhi = th;
      i8_t* t8 = hB8; hB8 = (i8_t*)hA8; hA8 = t8;
    }
    write_traj<<<(M + 255) / 256, 256, 0, st>>>(
        last_pos + base * 2, B.deltaAll, b2, out + base * TSTEP * 2, M);
  };

  for (int i = 0; i < NCHUNK; ++i) {
    const int s = i % NSTR;
    run_chunk(str[s], cb[s], (size_t)i * M);
  }

  // ---- join secondary streams back to origin ----
  if (NSTR > 1) {
    for (int s = 1; s < NSTR; ++s) {
      hipEventRecord(eJoin[s], str[s]);
      hipStreamWaitEvent(stream, eJoin[s], 0);
    }
    // handles intentionally not destroyed: destroying a stream/event that
    // participated in an active capture is unsafe; the harness makes only a
    // few kernel_launch calls, so the leak is bounded and benign.
  }
  (void)in_sizes; (void)n_in; (void)out_size;
}